// Round 1
// baseline (20194.682 us; speedup 1.0000x reference)
//
#include <hip/hip_runtime.h>
#include <math.h>

#define BB 2
#define SS 1024
#define HH 768
#define NHEAD 12
#define HDIM 64
#define NLAYER 4
#define VV 32000
#define MROWS (BB*SS)

// ---------------- embedding ----------------
__global__ void embed_kernel(const int* __restrict__ ids,
                             const float* __restrict__ bpe,
                             const float* __restrict__ pos,
                             float* __restrict__ h) {
    int row = blockIdx.x;              // 0..B*S-1
    int s = row % SS;
    int id = ids[row];
    const float* brow = bpe + (size_t)id * HH;
    const float* prow = pos + (size_t)s * HH;
    float* hrow = h + (size_t)row * HH;
    for (int t = threadIdx.x; t < HH; t += blockDim.x)
        hrow[t] = brow[t] + prow[t];
}

// ---------------- generic tiled f32 GEMM: C = A[MxK] * W[KxN] (+bias) (+gelu) ----
// All M,N,K used are multiples of 16 (M=2048; N in {2304,768,3072,32000}; K in {768,3072}).
template <int ACT>
__global__ void gemm_kernel(const float* __restrict__ A,
                            const float* __restrict__ W,
                            const float* __restrict__ bias,
                            float* __restrict__ C,
                            int M, int N, int K) {
    __shared__ float As[16][17];
    __shared__ float Bs[16][17];
    int tx = threadIdx.x, ty = threadIdx.y;
    int row = blockIdx.y * 16 + ty;
    int col = blockIdx.x * 16 + tx;
    float acc = 0.0f;
    for (int kt = 0; kt < K; kt += 16) {
        As[ty][tx] = A[(size_t)row * K + kt + tx];
        Bs[ty][tx] = W[(size_t)(kt + ty) * N + col];
        __syncthreads();
#pragma unroll
        for (int i = 0; i < 16; ++i)
            acc += As[ty][i] * Bs[i][tx];
        __syncthreads();
    }
    if (bias) acc += bias[col];
    if (ACT == 1)  // exact gelu
        acc = 0.5f * acc * (1.0f + erff(acc * 0.70710678118654752f));
    C[(size_t)row * N + col] = acc;
}

// ---------------- attention (one block = one (b, head, q-row)) ----------------
__global__ void attn_kernel(const float* __restrict__ qkv,
                            const float* __restrict__ seq_mask,
                            float* __restrict__ av) {
    int q = blockIdx.x;
    int hd = blockIdx.y;
    int b = blockIdx.z;
    int t = threadIdx.x;               // 64 threads = 1 wave

    __shared__ float qs[HDIM];
    __shared__ float sc[SS];

    const size_t rowstride = 3 * HH;
    const float* qrow = qkv + ((size_t)(b * SS + q)) * rowstride + hd * HDIM;
    if (t < HDIM) qs[t] = qrow[t];
    __syncthreads();

    // scores for k = t, t+64, ...
    for (int k = t; k < SS; k += 64) {
        const float* krow = qkv + ((size_t)(b * SS + k)) * rowstride + HH + hd * HDIM;
        float dot = 0.0f;
#pragma unroll
        for (int d = 0; d < HDIM; ++d) dot += qs[d] * krow[d];
        float m = (k <= q ? 1.0f : 0.0f) * seq_mask[b * SS + k];
        sc[k] = dot * 0.125f + (1.0f - m) * (-1e9f);
    }
    __syncthreads();

    // wave-wide max
    float mx = -INFINITY;
    for (int k = t; k < SS; k += 64) mx = fmaxf(mx, sc[k]);
#pragma unroll
    for (int off = 32; off; off >>= 1) mx = fmaxf(mx, __shfl_down(mx, off));
    mx = __shfl(mx, 0);

    float sum = 0.0f;
    for (int k = t; k < SS; k += 64) {
        float e = expf(sc[k] - mx);
        sc[k] = e;
        sum += e;
    }
#pragma unroll
    for (int off = 32; off; off >>= 1) sum += __shfl_down(sum, off);
    sum = __shfl(sum, 0);
    float inv = 1.0f / sum;
    __syncthreads();

    // PV: thread t owns output dim d = t
    float acc = 0.0f;
    for (int k = 0; k <= q; ++k)       // sc[k]==0 for masked k, k>q exp underflows to 0
        acc += sc[k] * qkv[((size_t)(b * SS + k)) * rowstride + 2 * HH + hd * HDIM + t];
    av[((size_t)(b * SS + q)) * HH + hd * HDIM + t] = acc * inv;
}

// ---------------- residual add + layernorm (in-place on h) ----------------
__global__ void add_ln_kernel(float* __restrict__ h,
                              const float* __restrict__ a,
                              const float* __restrict__ g,
                              const float* __restrict__ bta) {
    int row = blockIdx.x;
    int t = threadIdx.x;               // 256 threads, 3 elems each (H=768)
    __shared__ float red[256];
    size_t base = (size_t)row * HH;
    float x0 = h[base + t]       + a[base + t];
    float x1 = h[base + t + 256] + a[base + t + 256];
    float x2 = h[base + t + 512] + a[base + t + 512];

    red[t] = x0 + x1 + x2;
    __syncthreads();
    for (int o = 128; o; o >>= 1) { if (t < o) red[t] += red[t + o]; __syncthreads(); }
    float mean = red[0] * (1.0f / 768.0f);
    __syncthreads();

    float d0 = x0 - mean, d1 = x1 - mean, d2 = x2 - mean;
    red[t] = d0 * d0 + d1 * d1 + d2 * d2;
    __syncthreads();
    for (int o = 128; o; o >>= 1) { if (t < o) red[t] += red[t + o]; __syncthreads(); }
    float var = red[0] * (1.0f / 768.0f);
    float inv = 1.0f / sqrtf(var + 1e-5f);

    h[base + t]       = g[t]       * d0 * inv + bta[t];
    h[base + t + 256] = g[t + 256] * d1 * inv + bta[t + 256];
    h[base + t + 512] = g[t + 512] * d2 * inv + bta[t + 512];
}

// ---------------- row softmax over V=32000 ----------------
__global__ void softmax_v_kernel(const float* __restrict__ score,
                                 float* __restrict__ prob) {
    int row = blockIdx.x;
    int t = threadIdx.x;               // 256 threads
    __shared__ float red[256];
    const float* sr = score + (size_t)row * VV;
    float* pr = prob + (size_t)row * VV;

    float mx = -INFINITY;
    for (int i = t; i < VV; i += 256) mx = fmaxf(mx, sr[i]);
    red[t] = mx; __syncthreads();
    for (int o = 128; o; o >>= 1) { if (t < o) red[t] = fmaxf(red[t], red[t + o]); __syncthreads(); }
    mx = red[0];
    __syncthreads();

    float s = 0.0f;
    for (int i = t; i < VV; i += 256) s += expf(sr[i] - mx);
    red[t] = s; __syncthreads();
    for (int o = 128; o; o >>= 1) { if (t < o) red[t] += red[t + o]; __syncthreads(); }
    float inv = 1.0f / red[0];

    for (int i = t; i < VV; i += 256) pr[i] = expf(sr[i] - mx) * inv;
}

extern "C" void kernel_launch(void* const* d_in, const int* in_sizes, int n_in,
                              void* d_out, int out_size, void* d_ws, size_t ws_size,
                              hipStream_t stream) {
    const int*   ids      = (const int*)d_in[0];
    const float* seq_mask = (const float*)d_in[1];
    const float* bpe      = (const float*)d_in[2];
    const float* pos      = (const float*)d_in[3];
    const float* qkv_w    = (const float*)d_in[4];
    const float* qkv_b    = (const float*)d_in[5];
    const float* res_w    = (const float*)d_in[6];
    const float* res_b    = (const float*)d_in[7];
    const float* ln1_g    = (const float*)d_in[8];
    const float* ln1_b    = (const float*)d_in[9];
    const float* ff1_w    = (const float*)d_in[10];
    const float* ff1_b    = (const float*)d_in[11];
    const float* ff2_w    = (const float*)d_in[12];
    const float* ff2_b    = (const float*)d_in[13];
    const float* ln2_g    = (const float*)d_in[14];
    const float* ln2_b    = (const float*)d_in[15];
    const float* pred_w   = (const float*)d_in[16];

    float* out_score = (float*)d_out;
    float* out_prob  = out_score + (size_t)MROWS * VV;

    // scratch layout (floats): h | a | qkv | av | mid
    const size_t n_h   = (size_t)MROWS * HH;
    const size_t n_qkv = (size_t)MROWS * 3 * HH;
    const size_t n_mid = (size_t)MROWS * 4 * HH;
    const size_t need_floats = n_h * 3 + n_qkv + n_mid;  // ~15.7M floats ~63MB

    float* ws = (ws_size >= need_floats * sizeof(float)) ? (float*)d_ws : out_prob;
    float* h   = ws;
    float* a   = h + n_h;
    float* qkv = a + n_h;
    float* av  = qkv + n_qkv;
    float* mid = av + n_h;

    embed_kernel<<<MROWS, 256, 0, stream>>>(ids, bpe, pos, h);

    for (int l = 0; l < NLAYER; ++l) {
        gemm_kernel<0><<<dim3(3 * HH / 16, MROWS / 16), dim3(16, 16), 0, stream>>>(
            h, qkv_w + (size_t)l * HH * 3 * HH, qkv_b + (size_t)l * 3 * HH, qkv,
            MROWS, 3 * HH, HH);
        attn_kernel<<<dim3(SS, NHEAD, BB), 64, 0, stream>>>(qkv, seq_mask, av);
        gemm_kernel<0><<<dim3(HH / 16, MROWS / 16), dim3(16, 16), 0, stream>>>(
            av, res_w + (size_t)l * HH * HH, res_b + (size_t)l * HH, a,
            MROWS, HH, HH);
        add_ln_kernel<<<MROWS, 256, 0, stream>>>(h, a, ln1_g + (size_t)l * HH, ln1_b + (size_t)l * HH);
        gemm_kernel<1><<<dim3(4 * HH / 16, MROWS / 16), dim3(16, 16), 0, stream>>>(
            h, ff1_w + (size_t)l * HH * 4 * HH, ff1_b + (size_t)l * 4 * HH, mid,
            MROWS, 4 * HH, HH);
        gemm_kernel<0><<<dim3(HH / 16, MROWS / 16), dim3(16, 16), 0, stream>>>(
            mid, ff2_w + (size_t)l * 4 * HH * HH, ff2_b + (size_t)l * HH, a,
            MROWS, HH, 4 * HH);
        add_ln_kernel<<<MROWS, 256, 0, stream>>>(h, a, ln2_g + (size_t)l * HH, ln2_b + (size_t)l * HH);
    }

    gemm_kernel<0><<<dim3(VV / 16, MROWS / 16), dim3(16, 16), 0, stream>>>(
        h, pred_w, nullptr, out_score, MROWS, VV, HH);
    softmax_v_kernel<<<MROWS, 256, 0, stream>>>(out_score, out_prob);
}

// Round 2
// 12581.608 us; speedup vs baseline: 1.6051x; 1.6051x over previous
//
#include <hip/hip_runtime.h>
#include <math.h>

#define BB 2
#define SS 1024
#define HH 768
#define NHEAD 12
#define HDIM 64
#define NLAYER 4
#define VV 32000
#define MROWS (BB*SS)

typedef unsigned short u16;
typedef __attribute__((ext_vector_type(8))) short short8;
typedef __attribute__((ext_vector_type(4))) float f32x4;
typedef __attribute__((ext_vector_type(4))) unsigned short u16x4;

__device__ __forceinline__ u16 f2bf(float f) {
    union { float f; unsigned u; } x; x.f = f;
    unsigned r = (x.u + 0x7fff + ((x.u >> 16) & 1)) >> 16;
    return (u16)r;
}

__device__ __forceinline__ void gload_lds16(const u16* g, u16* l) {
    __builtin_amdgcn_global_load_lds((const __attribute__((address_space(1))) void*)g,
                                     (__attribute__((address_space(3))) void*)l, 16, 0, 0);
}

// ---------------- weight convert + transpose: W[K][N] f32 -> Wt[N][K] bf16 ----
__global__ void conv_transpose(const float* __restrict__ W, u16* __restrict__ Wt,
                               int K, int N) {
    int l = blockIdx.z;
    W  += (size_t)l * K * N;
    Wt += (size_t)l * K * N;
    __shared__ u16 tile[32][33];
    int k0 = blockIdx.y * 32, n0 = blockIdx.x * 32;
    int tx = threadIdx.x, ty = threadIdx.y;   // 32 x 8
#pragma unroll
    for (int i = 0; i < 4; ++i)
        tile[ty + 8*i][tx] = f2bf(W[(size_t)(k0 + ty + 8*i) * N + n0 + tx]);
    __syncthreads();
#pragma unroll
    for (int i = 0; i < 4; ++i)
        Wt[(size_t)(n0 + ty + 8*i) * K + k0 + tx] = tile[tx][ty + 8*i];
}

// ---------------- embedding: h f32 + hb bf16 ----------------
__global__ void embed_kernel(const int* __restrict__ ids,
                             const float* __restrict__ bpe,
                             const float* __restrict__ pos,
                             float* __restrict__ h, u16* __restrict__ hb) {
    int row = blockIdx.x;
    int s = row % SS;
    int id = ids[row];
    const float4* br = (const float4*)(bpe + (size_t)id * HH);
    const float4* pr = (const float4*)(pos + (size_t)s * HH);
    float4* hr = (float4*)(h + (size_t)row * HH);
    u16x4* hbr = (u16x4*)(hb + (size_t)row * HH);
    int t = threadIdx.x;                  // 192 threads, 1 float4 each
    float4 a = br[t], c = pr[t];
    a.x += c.x; a.y += c.y; a.z += c.z; a.w += c.w;
    hr[t] = a;
    u16x4 u; u[0] = f2bf(a.x); u[1] = f2bf(a.y); u[2] = f2bf(a.z); u[3] = f2bf(a.w);
    hbr[t] = u;
}

// ---------------- MFMA GEMM: C[M][N] = A[M][K](bf16) * Wt[N][K](bf16)^T ------
// m97 structure: 128x128 tile, BK=32, 4 waves (2x2), 4x4 16x16 frags per wave.
template<int ACT, int WF32, int WBF>
__global__ __launch_bounds__(256) void mfma_gemm(
    const u16* __restrict__ A, const u16* __restrict__ Wt,
    const float* __restrict__ bias, float* __restrict__ C,
    u16* __restrict__ Cb, int M, int N, int K) {
    __shared__ u16 As[128 * 32];
    __shared__ u16 Bs[128 * 32];
    const int tid = threadIdx.x;
    const int lane = tid & 63;
    const int wid = tid >> 6;
    const int brow = blockIdx.y * 128;
    const int bcol = blockIdx.x * 128;
    const int wr = (wid >> 1) * 64;
    const int wc = (wid & 1) * 64;
    f32x4 acc[4][4] = {};

    const u16* Abase = A + (size_t)brow * K;
    const u16* Bbase = Wt + (size_t)bcol * K;
    const int lrow = lane & 15;
    const int lk = (lane >> 4) * 8;

    for (int kt = 0; kt < K; kt += 32) {
        __syncthreads();
#pragma unroll
        for (int i = 0; i < 2; ++i) {
            int c = tid + i * 256;
            int r = c >> 2;
            int off = (c & 3) * 8;
            gload_lds16(Abase + (size_t)r * K + kt + off, As + c * 8);
            gload_lds16(Bbase + (size_t)r * K + kt + off, Bs + c * 8);
        }
        __syncthreads();
        short8 a[4], b[4];
#pragma unroll
        for (int m = 0; m < 4; ++m)
            a[m] = *(const short8*)(As + (wr + m * 16 + lrow) * 32 + lk);
#pragma unroll
        for (int n = 0; n < 4; ++n)
            b[n] = *(const short8*)(Bs + (wc + n * 16 + lrow) * 32 + lk);
#pragma unroll
        for (int m = 0; m < 4; ++m)
#pragma unroll
            for (int n = 0; n < 4; ++n)
                acc[m][n] = __builtin_amdgcn_mfma_f32_16x16x32_bf16(a[m], b[n], acc[m][n], 0, 0, 0);
    }

    const int lr4 = (lane >> 4) * 4;
#pragma unroll
    for (int n = 0; n < 4; ++n) {
        int col = bcol + wc + n * 16 + lrow;
        float bv = bias ? bias[col] : 0.f;
#pragma unroll
        for (int m = 0; m < 4; ++m) {
#pragma unroll
            for (int j = 0; j < 4; ++j) {
                int row = brow + wr + m * 16 + lr4 + j;
                float v = acc[m][n][j] + bv;
                if (ACT == 1) v = 0.5f * v * (1.f + erff(v * 0.70710678118654752f));
                if (WF32) C[(size_t)row * N + col] = v;
                if (WBF)  Cb[(size_t)row * N + col] = f2bf(v);
            }
        }
    }
}

// ---------------- tiled online-softmax attention ----------------
// block = 64 q-rows of one (b,head); 256 threads: lane owns (qi=t>>2, dg=t&3).
// Q row in regs (64 f32); K/V staged in XOR-swizzled LDS; per-lane partial PV
// over its 16 k-columns; 4-lane butterfly combine at the end.
__global__ __launch_bounds__(256) void attn_kernel(
    const float* __restrict__ qkv, const float* __restrict__ seq_mask,
    u16* __restrict__ av) {
    __shared__ float Ks[64 * 64];
    __shared__ float Vs[64 * 64];
    const int qb = blockIdx.x, hd = blockIdx.y, b = blockIdx.z;
    const int t = threadIdx.x;
    const int qi = t >> 2;
    const int dg = t & 3;
    const int q = qb * 64 + qi;
    const size_t rs = 3 * HH;

    const float* qrow = qkv + (size_t)(b * SS + q) * rs + hd * HDIM;
    float qreg[64];
#pragma unroll
    for (int u = 0; u < 16; ++u) {
        float4 v = *(const float4*)(qrow + u * 4);
        qreg[4 * u + 0] = v.x; qreg[4 * u + 1] = v.y;
        qreg[4 * u + 2] = v.z; qreg[4 * u + 3] = v.w;
    }
    float Oacc[64];
#pragma unroll
    for (int d = 0; d < 64; ++d) Oacc[d] = 0.f;
    float mrun = -INFINITY, lrun = 0.f;

    for (int kt = 0; kt <= qb; ++kt) {
        const int k0 = kt * 64;
        __syncthreads();
        // stage K,V tiles; float4 chunk c -> row r=c>>4, du=c&15, swizzle du^=(r>>4)&3
#pragma unroll
        for (int i = 0; i < 4; ++i) {
            int c = t + i * 256;
            int r = c >> 4, du = c & 15;
            int dusw = du ^ ((r >> 4) & 3);
            const float* krow = qkv + (size_t)(b * SS + k0 + r) * rs + HH + hd * HDIM;
            *(float4*)(Ks + r * 64 + dusw * 4) = *(const float4*)(krow + du * 4);
            *(float4*)(Vs + r * 64 + dusw * 4) = *(const float4*)(krow + HH + du * 4);
        }
        __syncthreads();

        float s[16];
#pragma unroll
        for (int j = 0; j < 16; ++j) {
            const int kl = dg * 16 + j;
            const int sw = dg;                 // kl>>4
            float dot = 0.f;
#pragma unroll
            for (int du = 0; du < 16; ++du) {
                float4 kv = *(const float4*)(Ks + kl * 64 + (du ^ sw) * 4);
                dot += qreg[du * 4 + 0] * kv.x + qreg[du * 4 + 1] * kv.y
                     + qreg[du * 4 + 2] * kv.z + qreg[du * 4 + 3] * kv.w;
            }
            int k = k0 + kl;
            float msk = (k <= q) ? seq_mask[b * SS + k] : 0.f;
            s[j] = dot * 0.125f + (1.f - msk) * (-1e9f);
        }
        float tmax = s[0];
#pragma unroll
        for (int j = 1; j < 16; ++j) tmax = fmaxf(tmax, s[j]);
        tmax = fmaxf(tmax, __shfl_xor(tmax, 1));
        tmax = fmaxf(tmax, __shfl_xor(tmax, 2));
        float mnew = fmaxf(mrun, tmax);
        float scale = expf(mrun - mnew);       // first tile: exp(-inf)=0
        float p[16];
        float psum = 0.f;
#pragma unroll
        for (int j = 0; j < 16; ++j) { p[j] = expf(s[j] - mnew); psum += p[j]; }
        psum += __shfl_xor(psum, 1);
        psum += __shfl_xor(psum, 2);
        lrun = lrun * scale + psum;
        mrun = mnew;
#pragma unroll
        for (int d = 0; d < 64; ++d) Oacc[d] *= scale;
        // partial PV over this lane's 16 k-columns
#pragma unroll
        for (int j = 0; j < 16; ++j) {
            const int kl = dg * 16 + j;
            const int sw = dg;
            float pj = p[j];
#pragma unroll
            for (int du = 0; du < 16; ++du) {
                float4 vv = *(const float4*)(Vs + kl * 64 + (du ^ sw) * 4);
                Oacc[du * 4 + 0] += pj * vv.x; Oacc[du * 4 + 1] += pj * vv.y;
                Oacc[du * 4 + 2] += pj * vv.z; Oacc[du * 4 + 3] += pj * vv.w;
            }
        }
    }
    // combine 4 partial sums per q-row
#pragma unroll
    for (int d = 0; d < 64; ++d) {
        Oacc[d] += __shfl_xor(Oacc[d], 1);
        Oacc[d] += __shfl_xor(Oacc[d], 2);
    }
    float inv = 1.f / lrun;
    u16* orow = av + (size_t)(b * SS + q) * HH + hd * HDIM;
#pragma unroll
    for (int u = 0; u < 64; ++u)
        if ((u >> 4) == dg) orow[u] = f2bf(Oacc[u] * inv);
}

// ---------------- residual add + layernorm: h f32 + hb bf16 ----------------
__global__ void add_ln_kernel(float* __restrict__ h, u16* __restrict__ hb,
                              const float* __restrict__ a,
                              const float* __restrict__ g,
                              const float* __restrict__ bta) {
    int row = blockIdx.x;
    int t = threadIdx.x;
    __shared__ float red[256];
    size_t base = (size_t)row * HH;
    float x0 = h[base + t]       + a[base + t];
    float x1 = h[base + t + 256] + a[base + t + 256];
    float x2 = h[base + t + 512] + a[base + t + 512];

    red[t] = x0 + x1 + x2;
    __syncthreads();
    for (int o = 128; o; o >>= 1) { if (t < o) red[t] += red[t + o]; __syncthreads(); }
    float mean = red[0] * (1.0f / 768.0f);
    __syncthreads();

    float d0 = x0 - mean, d1 = x1 - mean, d2 = x2 - mean;
    red[t] = d0 * d0 + d1 * d1 + d2 * d2;
    __syncthreads();
    for (int o = 128; o; o >>= 1) { if (t < o) red[t] += red[t + o]; __syncthreads(); }
    float var = red[0] * (1.0f / 768.0f);
    float inv = 1.0f / sqrtf(var + 1e-5f);

    float y0 = g[t]       * d0 * inv + bta[t];
    float y1 = g[t + 256] * d1 * inv + bta[t + 256];
    float y2 = g[t + 512] * d2 * inv + bta[t + 512];
    h[base + t] = y0;       hb[base + t] = f2bf(y0);
    h[base + t + 256] = y1; hb[base + t + 256] = f2bf(y1);
    h[base + t + 512] = y2; hb[base + t + 512] = f2bf(y2);
}

// ---------------- row softmax over V=32000 (float4) ----------------
__global__ void softmax_v_kernel(const float* __restrict__ score,
                                 float* __restrict__ prob) {
    int row = blockIdx.x;
    int t = threadIdx.x;
    __shared__ float red[256];
    const float4* sr = (const float4*)(score + (size_t)row * VV);
    float4* pr = (float4*)(prob + (size_t)row * VV);
    const int n4 = VV / 4;

    float mx = -INFINITY;
    for (int i = t; i < n4; i += 256) {
        float4 v = sr[i];
        mx = fmaxf(mx, fmaxf(fmaxf(v.x, v.y), fmaxf(v.z, v.w)));
    }
    red[t] = mx; __syncthreads();
    for (int o = 128; o; o >>= 1) { if (t < o) red[t] = fmaxf(red[t], red[t + o]); __syncthreads(); }
    mx = red[0];
    __syncthreads();

    float s = 0.f;
    for (int i = t; i < n4; i += 256) {
        float4 v = sr[i];
        s += expf(v.x - mx) + expf(v.y - mx) + expf(v.z - mx) + expf(v.w - mx);
    }
    red[t] = s; __syncthreads();
    for (int o = 128; o; o >>= 1) { if (t < o) red[t] += red[t + o]; __syncthreads(); }
    float inv = 1.0f / red[0];

    for (int i = t; i < n4; i += 256) {
        float4 v = sr[i];
        float4 o4;
        o4.x = expf(v.x - mx) * inv; o4.y = expf(v.y - mx) * inv;
        o4.z = expf(v.z - mx) * inv; o4.w = expf(v.w - mx) * inv;
        pr[i] = o4;
    }
}

extern "C" void kernel_launch(void* const* d_in, const int* in_sizes, int n_in,
                              void* d_out, int out_size, void* d_ws, size_t ws_size,
                              hipStream_t stream) {
    const int*   ids      = (const int*)d_in[0];
    const float* seq_mask = (const float*)d_in[1];
    const float* bpe      = (const float*)d_in[2];
    const float* pos      = (const float*)d_in[3];
    const float* qkv_w    = (const float*)d_in[4];
    const float* qkv_b    = (const float*)d_in[5];
    const float* res_w    = (const float*)d_in[6];
    const float* res_b    = (const float*)d_in[7];
    const float* ln1_g    = (const float*)d_in[8];
    const float* ln1_b    = (const float*)d_in[9];
    const float* ff1_w    = (const float*)d_in[10];
    const float* ff1_b    = (const float*)d_in[11];
    const float* ff2_w    = (const float*)d_in[12];
    const float* ff2_b    = (const float*)d_in[13];
    const float* ln2_g    = (const float*)d_in[14];
    const float* ln2_b    = (const float*)d_in[15];
    const float* pred_w   = (const float*)d_in[16];

    float* out_score = (float*)d_out;
    float* out_prob  = out_score + (size_t)MROWS * VV;

    // arena layout
    size_t off = 0;
    auto take = [&](size_t bytes) -> size_t {
        size_t p = off; off += (bytes + 255) & ~(size_t)255; return p;
    };
    const size_t o_qkvT = take((size_t)NLAYER * HH * 3 * HH * 2);
    const size_t o_resT = take((size_t)NLAYER * HH * HH * 2);
    const size_t o_ff1T = take((size_t)NLAYER * HH * 4 * HH * 2);
    const size_t o_ff2T = take((size_t)NLAYER * 4 * HH * HH * 2);
    const size_t o_predT = take((size_t)HH * VV * 2);
    const size_t o_h    = take((size_t)MROWS * HH * 4);
    const size_t o_a    = take((size_t)MROWS * HH * 4);
    const size_t o_qkv  = take((size_t)MROWS * 3 * HH * 4);
    const size_t o_hb   = take((size_t)MROWS * HH * 2);
    const size_t o_avb  = take((size_t)MROWS * HH * 2);
    const size_t o_midb = take((size_t)MROWS * 4 * HH * 2);
    const size_t need = off;

    char* arena = (ws_size >= need) ? (char*)d_ws : (char*)out_prob;
    u16*   qkvT = (u16*)(arena + o_qkvT);
    u16*   resT = (u16*)(arena + o_resT);
    u16*   ff1T = (u16*)(arena + o_ff1T);
    u16*   ff2T = (u16*)(arena + o_ff2T);
    u16*   predT = (u16*)(arena + o_predT);
    float* h    = (float*)(arena + o_h);
    float* a    = (float*)(arena + o_a);
    float* qkv  = (float*)(arena + o_qkv);
    u16*   hb   = (u16*)(arena + o_hb);
    u16*   avb  = (u16*)(arena + o_avb);
    u16*   midb = (u16*)(arena + o_midb);

    dim3 tb(32, 8);
    conv_transpose<<<dim3(3 * HH / 32, HH / 32, NLAYER), tb, 0, stream>>>(qkv_w, qkvT, HH, 3 * HH);
    conv_transpose<<<dim3(HH / 32, HH / 32, NLAYER), tb, 0, stream>>>(res_w, resT, HH, HH);
    conv_transpose<<<dim3(4 * HH / 32, HH / 32, NLAYER), tb, 0, stream>>>(ff1_w, ff1T, HH, 4 * HH);
    conv_transpose<<<dim3(HH / 32, 4 * HH / 32, NLAYER), tb, 0, stream>>>(ff2_w, ff2T, 4 * HH, HH);
    conv_transpose<<<dim3(VV / 32, HH / 32, 1), tb, 0, stream>>>(pred_w, predT, HH, VV);

    embed_kernel<<<MROWS, 192, 0, stream>>>(ids, bpe, pos, h, hb);

    for (int l = 0; l < NLAYER; ++l) {
        mfma_gemm<0, 1, 0><<<dim3(3 * HH / 128, MROWS / 128), 256, 0, stream>>>(
            hb, qkvT + (size_t)l * HH * 3 * HH, qkv_b + (size_t)l * 3 * HH,
            qkv, nullptr, MROWS, 3 * HH, HH);
        attn_kernel<<<dim3(SS / 64, NHEAD, BB), 256, 0, stream>>>(qkv, seq_mask, avb);
        mfma_gemm<0, 1, 0><<<dim3(HH / 128, MROWS / 128), 256, 0, stream>>>(
            avb, resT + (size_t)l * HH * HH, res_b + (size_t)l * HH,
            a, nullptr, MROWS, HH, HH);
        add_ln_kernel<<<MROWS, 256, 0, stream>>>(h, hb, a,
            ln1_g + (size_t)l * HH, ln1_b + (size_t)l * HH);
        mfma_gemm<1, 0, 1><<<dim3(4 * HH / 128, MROWS / 128), 256, 0, stream>>>(
            hb, ff1T + (size_t)l * HH * 4 * HH, ff1_b + (size_t)l * 4 * HH,
            nullptr, midb, MROWS, 4 * HH, HH);
        mfma_gemm<0, 1, 0><<<dim3(HH / 128, MROWS / 128), 256, 0, stream>>>(
            midb, ff2T + (size_t)l * 4 * HH * HH, ff2_b + (size_t)l * HH,
            a, nullptr, MROWS, HH, 4 * HH);
        add_ln_kernel<<<MROWS, 256, 0, stream>>>(h, hb, a,
            ln2_g + (size_t)l * HH, ln2_b + (size_t)l * HH);
    }

    mfma_gemm<0, 1, 0><<<dim3(VV / 128, MROWS / 128), 256, 0, stream>>>(
        hb, predT, nullptr, out_score, nullptr, MROWS, VV, HH);
    softmax_v_kernel<<<MROWS, 256, 0, stream>>>(out_score, out_prob);
}

// Round 3
// 12228.535 us; speedup vs baseline: 1.6514x; 1.0289x over previous
//
#include <hip/hip_runtime.h>
#include <math.h>

#define BB 2
#define SS 1024
#define HH 768
#define NHEAD 12
#define HDIM 64
#define NLAYER 4
#define VV 32000
#define MROWS (BB*SS)

typedef unsigned short u16;
typedef __attribute__((ext_vector_type(8))) short short8;
typedef __attribute__((ext_vector_type(4))) float f32x4;
typedef __attribute__((ext_vector_type(4))) unsigned short u16x4;

__device__ __forceinline__ u16 f2bf(float f) {
    union { float f; unsigned u; } x; x.f = f;
    unsigned r = (x.u + 0x7fff + ((x.u >> 16) & 1)) >> 16;
    return (u16)r;
}

__device__ __forceinline__ void gload_lds16(const u16* g, u16* l) {
    __builtin_amdgcn_global_load_lds((const __attribute__((address_space(1))) void*)g,
                                     (__attribute__((address_space(3))) void*)l, 16, 0, 0);
}

// ---------------- weight convert + transpose: W[K][N] f32 -> Wt[N][K] bf16 ----
__global__ void conv_transpose(const float* __restrict__ W, u16* __restrict__ Wt,
                               int K, int N) {
    int l = blockIdx.z;
    W  += (size_t)l * K * N;
    Wt += (size_t)l * K * N;
    __shared__ u16 tile[32][33];
    int k0 = blockIdx.y * 32, n0 = blockIdx.x * 32;
    int tx = threadIdx.x, ty = threadIdx.y;   // 32 x 8
#pragma unroll
    for (int i = 0; i < 4; ++i)
        tile[ty + 8*i][tx] = f2bf(W[(size_t)(k0 + ty + 8*i) * N + n0 + tx]);
    __syncthreads();
#pragma unroll
    for (int i = 0; i < 4; ++i)
        Wt[(size_t)(n0 + ty + 8*i) * K + k0 + tx] = tile[tx][ty + 8*i];
}

// ---------------- embedding: h f32 + hb bf16 ----------------
__global__ void embed_kernel(const int* __restrict__ ids,
                             const float* __restrict__ bpe,
                             const float* __restrict__ pos,
                             float* __restrict__ h, u16* __restrict__ hb) {
    int row = blockIdx.x;
    int s = row % SS;
    int id = ids[row];
    const float4* br = (const float4*)(bpe + (size_t)id * HH);
    const float4* pr = (const float4*)(pos + (size_t)s * HH);
    float4* hr = (float4*)(h + (size_t)row * HH);
    u16x4* hbr = (u16x4*)(hb + (size_t)row * HH);
    int t = threadIdx.x;                  // 192 threads, 1 float4 each
    float4 a = br[t], c = pr[t];
    a.x += c.x; a.y += c.y; a.z += c.z; a.w += c.w;
    hr[t] = a;
    u16x4 u; u[0] = f2bf(a.x); u[1] = f2bf(a.y); u[2] = f2bf(a.z); u[3] = f2bf(a.w);
    hbr[t] = u;
}

// ---------------- MFMA GEMM: C[M][N] = A[M][K](bf16) * Wt[N][K](bf16)^T ------
template<int ACT, int WF32, int WBF>
__global__ __launch_bounds__(256) void mfma_gemm(
    const u16* __restrict__ A, const u16* __restrict__ Wt,
    const float* __restrict__ bias, float* __restrict__ C,
    u16* __restrict__ Cb, int M, int N, int K) {
    __shared__ u16 As[128 * 32];
    __shared__ u16 Bs[128 * 32];
    const int tid = threadIdx.x;
    const int lane = tid & 63;
    const int wid = tid >> 6;
    const int brow = blockIdx.y * 128;
    const int bcol = blockIdx.x * 128;
    const int wr = (wid >> 1) * 64;
    const int wc = (wid & 1) * 64;
    f32x4 acc[4][4] = {};

    const u16* Abase = A + (size_t)brow * K;
    const u16* Bbase = Wt + (size_t)bcol * K;
    const int lrow = lane & 15;
    const int lk = (lane >> 4) * 8;

    for (int kt = 0; kt < K; kt += 32) {
        __syncthreads();
#pragma unroll
        for (int i = 0; i < 2; ++i) {
            int c = tid + i * 256;
            int r = c >> 2;
            int off = (c & 3) * 8;
            gload_lds16(Abase + (size_t)r * K + kt + off, As + c * 8);
            gload_lds16(Bbase + (size_t)r * K + kt + off, Bs + c * 8);
        }
        __syncthreads();
        short8 a[4], b[4];
#pragma unroll
        for (int m = 0; m < 4; ++m)
            a[m] = *(const short8*)(As + (wr + m * 16 + lrow) * 32 + lk);
#pragma unroll
        for (int n = 0; n < 4; ++n)
            b[n] = *(const short8*)(Bs + (wc + n * 16 + lrow) * 32 + lk);
#pragma unroll
        for (int m = 0; m < 4; ++m)
#pragma unroll
            for (int n = 0; n < 4; ++n)
                acc[m][n] = __builtin_amdgcn_mfma_f32_16x16x32_bf16(a[m], b[n], acc[m][n], 0, 0, 0);
    }

    const int lr4 = (lane >> 4) * 4;
#pragma unroll
    for (int n = 0; n < 4; ++n) {
        int col = bcol + wc + n * 16 + lrow;
        float bv = bias ? bias[col] : 0.f;
#pragma unroll
        for (int m = 0; m < 4; ++m) {
#pragma unroll
            for (int j = 0; j < 4; ++j) {
                int row = brow + wr + m * 16 + lr4 + j;
                float v = acc[m][n][j] + bv;
                if (ACT == 1) v = 0.5f * v * (1.f + erff(v * 0.70710678118654752f));
                if (WF32) C[(size_t)row * N + col] = v;
                if (WBF)  Cb[(size_t)row * N + col] = f2bf(v);
            }
        }
    }
}

// ---------------- tiled online-softmax attention (no spill) ----------------
// block = 64 q-rows of one (b,head); 256 threads; thread t: qi=t>>2, sub=t&3.
// Lane computes scores for k-cols [16*sub,16*sub+16), shares p via LDS Ps
// (wave-local: 4 writer lanes + reader of each qi are in the same wave),
// accumulates PV for output dims [16*sub,16*sub+16) only (Oacc[16]).
__global__ __launch_bounds__(256) void attn_kernel(
    const float* __restrict__ qkv, const float* __restrict__ seq_mask,
    u16* __restrict__ av) {
    __shared__ float Ks[64 * 64];
    __shared__ float Vs[64 * 64];
    __shared__ float Ps[64 * 68];   // +4 pad breaks bank aliasing
    const int qb = blockIdx.x, hd = blockIdx.y, b = blockIdx.z;
    const int t = threadIdx.x;
    const int qi = t >> 2;
    const int sub = t & 3;
    const int q = qb * 64 + qi;
    const size_t rs = 3 * HH;

    const float* qrow = qkv + (size_t)(b * SS + q) * rs + hd * HDIM;
    float qreg[64];
#pragma unroll
    for (int u = 0; u < 16; ++u) {
        float4 v = *(const float4*)(qrow + u * 4);
        qreg[4*u+0] = v.x; qreg[4*u+1] = v.y; qreg[4*u+2] = v.z; qreg[4*u+3] = v.w;
    }
    float Oacc[16];
#pragma unroll
    for (int d = 0; d < 16; ++d) Oacc[d] = 0.f;
    float mrun = -INFINITY, lrun = 0.f;

    for (int kt = 0; kt <= qb; ++kt) {
        const int k0 = kt * 64;
        __syncthreads();
        // stage K,V tiles; float4 chunk c -> row r=c>>4, du=c&15, swizzle du^=(r>>4)
#pragma unroll
        for (int i = 0; i < 4; ++i) {
            int c = t + i * 256;
            int r = c >> 4, du = c & 15;
            int dusw = du ^ (r >> 4);
            const float* krow = qkv + (size_t)(b * SS + k0 + r) * rs + HH + hd * HDIM;
            *(float4*)(Ks + r * 64 + dusw * 4) = *(const float4*)(krow + du * 4);
            *(float4*)(Vs + r * 64 + dusw * 4) = *(const float4*)(krow + HH + du * 4);
        }
        __syncthreads();

        // scores for this lane's 16 k-cols
        float p[16];
        float tmax = -INFINITY;
#pragma unroll
        for (int j = 0; j < 16; ++j) {
            const int kl = sub * 16 + j;
            float dot = 0.f;
#pragma unroll
            for (int du = 0; du < 16; ++du) {
                float4 kv = *(const float4*)(Ks + kl * 64 + ((du ^ sub) * 4));
                dot += qreg[du*4+0]*kv.x + qreg[du*4+1]*kv.y
                     + qreg[du*4+2]*kv.z + qreg[du*4+3]*kv.w;
            }
            int k = k0 + kl;
            float msk = (k <= q) ? seq_mask[b * SS + k] : 0.f;
            p[j] = dot * 0.125f + (1.f - msk) * (-1e9f);
            tmax = fmaxf(tmax, p[j]);
        }
        tmax = fmaxf(tmax, __shfl_xor(tmax, 1));
        tmax = fmaxf(tmax, __shfl_xor(tmax, 2));
        float mnew = fmaxf(mrun, tmax);
        float scale = __expf(mrun - mnew);     // first tile: exp(-inf)=0
        float psum = 0.f;
#pragma unroll
        for (int j = 0; j < 16; ++j) { p[j] = __expf(p[j] - mnew); psum += p[j]; }
        psum += __shfl_xor(psum, 1);
        psum += __shfl_xor(psum, 2);
        lrun = lrun * scale + psum;
        mrun = mnew;
        // publish p (wave-local consumers; per-wave DS ops are in-order)
#pragma unroll
        for (int j4 = 0; j4 < 4; ++j4) {
            float4 pw;
            pw.x = p[j4*4+0]; pw.y = p[j4*4+1]; pw.z = p[j4*4+2]; pw.w = p[j4*4+3];
            *(float4*)(Ps + qi * 68 + sub * 16 + j4 * 4) = pw;
        }
#pragma unroll
        for (int d = 0; d < 16; ++d) Oacc[d] *= scale;
        // PV: all 64 k's, own dims [16*sub, 16*sub+16)
#pragma unroll
        for (int k4 = 0; k4 < 16; ++k4) {
            float4 pv = *(const float4*)(Ps + qi * 68 + k4 * 4);
#pragma unroll
            for (int c = 0; c < 4; ++c) {
                int k = k4 * 4 + c;
                float pk = (c==0) ? pv.x : (c==1) ? pv.y : (c==2) ? pv.z : pv.w;
                int sw = k >> 4;
#pragma unroll
                for (int d4 = 0; d4 < 4; ++d4) {
                    float4 vv = *(const float4*)(Vs + k * 64 + (((sub*4+d4) ^ sw) * 4));
                    Oacc[d4*4+0] += pk * vv.x; Oacc[d4*4+1] += pk * vv.y;
                    Oacc[d4*4+2] += pk * vv.z; Oacc[d4*4+3] += pk * vv.w;
                }
            }
        }
    }
    float inv = 1.f / lrun;
    u16* orow = av + (size_t)(b * SS + q) * HH + hd * HDIM + sub * 16;
#pragma unroll
    for (int d4 = 0; d4 < 4; ++d4) {
        u16x4 o;
        o[0] = f2bf(Oacc[d4*4+0]*inv); o[1] = f2bf(Oacc[d4*4+1]*inv);
        o[2] = f2bf(Oacc[d4*4+2]*inv); o[3] = f2bf(Oacc[d4*4+3]*inv);
        *(u16x4*)(orow + d4*4) = o;
    }
}

// ---------------- residual add + layernorm: h f32 + hb bf16 ----------------
__global__ void add_ln_kernel(float* __restrict__ h, u16* __restrict__ hb,
                              const float* __restrict__ a,
                              const float* __restrict__ g,
                              const float* __restrict__ bta) {
    int row = blockIdx.x;
    int t = threadIdx.x;
    __shared__ float red[256];
    size_t base = (size_t)row * HH;
    float x0 = h[base + t]       + a[base + t];
    float x1 = h[base + t + 256] + a[base + t + 256];
    float x2 = h[base + t + 512] + a[base + t + 512];

    red[t] = x0 + x1 + x2;
    __syncthreads();
    for (int o = 128; o; o >>= 1) { if (t < o) red[t] += red[t + o]; __syncthreads(); }
    float mean = red[0] * (1.0f / 768.0f);
    __syncthreads();

    float d0 = x0 - mean, d1 = x1 - mean, d2 = x2 - mean;
    red[t] = d0 * d0 + d1 * d1 + d2 * d2;
    __syncthreads();
    for (int o = 128; o; o >>= 1) { if (t < o) red[t] += red[t + o]; __syncthreads(); }
    float var = red[0] * (1.0f / 768.0f);
    float inv = 1.0f / sqrtf(var + 1e-5f);

    float y0 = g[t]       * d0 * inv + bta[t];
    float y1 = g[t + 256] * d1 * inv + bta[t + 256];
    float y2 = g[t + 512] * d2 * inv + bta[t + 512];
    h[base + t] = y0;       hb[base + t] = f2bf(y0);
    h[base + t + 256] = y1; hb[base + t + 256] = f2bf(y1);
    h[base + t + 512] = y2; hb[base + t + 512] = f2bf(y2);
}

// ---------------- row softmax over V=32000 (float4) ----------------
__global__ void softmax_v_kernel(const float* __restrict__ score,
                                 float* __restrict__ prob) {
    int row = blockIdx.x;
    int t = threadIdx.x;
    __shared__ float red[256];
    const float4* sr = (const float4*)(score + (size_t)row * VV);
    float4* pr = (float4*)(prob + (size_t)row * VV);
    const int n4 = VV / 4;

    float mx = -INFINITY;
    for (int i = t; i < n4; i += 256) {
        float4 v = sr[i];
        mx = fmaxf(mx, fmaxf(fmaxf(v.x, v.y), fmaxf(v.z, v.w)));
    }
    red[t] = mx; __syncthreads();
    for (int o = 128; o; o >>= 1) { if (t < o) red[t] = fmaxf(red[t], red[t + o]); __syncthreads(); }
    mx = red[0];
    __syncthreads();

    float s = 0.f;
    for (int i = t; i < n4; i += 256) {
        float4 v = sr[i];
        s += expf(v.x - mx) + expf(v.y - mx) + expf(v.z - mx) + expf(v.w - mx);
    }
    red[t] = s; __syncthreads();
    for (int o = 128; o; o >>= 1) { if (t < o) red[t] += red[t + o]; __syncthreads(); }
    float inv = 1.0f / red[0];

    for (int i = t; i < n4; i += 256) {
        float4 v = sr[i];
        float4 o4;
        o4.x = expf(v.x - mx) * inv; o4.y = expf(v.y - mx) * inv;
        o4.z = expf(v.z - mx) * inv; o4.w = expf(v.w - mx) * inv;
        pr[i] = o4;
    }
}

extern "C" void kernel_launch(void* const* d_in, const int* in_sizes, int n_in,
                              void* d_out, int out_size, void* d_ws, size_t ws_size,
                              hipStream_t stream) {
    const int*   ids      = (const int*)d_in[0];
    const float* seq_mask = (const float*)d_in[1];
    const float* bpe      = (const float*)d_in[2];
    const float* pos      = (const float*)d_in[3];
    const float* qkv_w    = (const float*)d_in[4];
    const float* qkv_b    = (const float*)d_in[5];
    const float* res_w    = (const float*)d_in[6];
    const float* res_b    = (const float*)d_in[7];
    const float* ln1_g    = (const float*)d_in[8];
    const float* ln1_b    = (const float*)d_in[9];
    const float* ff1_w    = (const float*)d_in[10];
    const float* ff1_b    = (const float*)d_in[11];
    const float* ff2_w    = (const float*)d_in[12];
    const float* ff2_b    = (const float*)d_in[13];
    const float* ln2_g    = (const float*)d_in[14];
    const float* ln2_b    = (const float*)d_in[15];
    const float* pred_w   = (const float*)d_in[16];

    float* out_score = (float*)d_out;
    float* out_prob  = out_score + (size_t)MROWS * VV;

    // arena layout
    size_t off = 0;
    auto take = [&](size_t bytes) -> size_t {
        size_t p = off; off += (bytes + 255) & ~(size_t)255; return p;
    };
    const size_t o_qkvT = take((size_t)NLAYER * HH * 3 * HH * 2);
    const size_t o_resT = take((size_t)NLAYER * HH * HH * 2);
    const size_t o_ff1T = take((size_t)NLAYER * HH * 4 * HH * 2);
    const size_t o_ff2T = take((size_t)NLAYER * 4 * HH * HH * 2);
    const size_t o_predT = take((size_t)HH * VV * 2);
    const size_t o_h    = take((size_t)MROWS * HH * 4);
    const size_t o_a    = take((size_t)MROWS * HH * 4);
    const size_t o_qkv  = take((size_t)MROWS * 3 * HH * 4);
    const size_t o_hb   = take((size_t)MROWS * HH * 2);
    const size_t o_avb  = take((size_t)MROWS * HH * 2);
    const size_t o_midb = take((size_t)MROWS * 4 * HH * 2);
    const size_t need = off;

    char* arena = (ws_size >= need) ? (char*)d_ws : (char*)out_prob;
    u16*   qkvT = (u16*)(arena + o_qkvT);
    u16*   resT = (u16*)(arena + o_resT);
    u16*   ff1T = (u16*)(arena + o_ff1T);
    u16*   ff2T = (u16*)(arena + o_ff2T);
    u16*   predT = (u16*)(arena + o_predT);
    float* h    = (float*)(arena + o_h);
    float* a    = (float*)(arena + o_a);
    float* qkv  = (float*)(arena + o_qkv);
    u16*   hb   = (u16*)(arena + o_hb);
    u16*   avb  = (u16*)(arena + o_avb);
    u16*   midb = (u16*)(arena + o_midb);

    dim3 tb(32, 8);
    conv_transpose<<<dim3(3 * HH / 32, HH / 32, NLAYER), tb, 0, stream>>>(qkv_w, qkvT, HH, 3 * HH);
    conv_transpose<<<dim3(HH / 32, HH / 32, NLAYER), tb, 0, stream>>>(res_w, resT, HH, HH);
    conv_transpose<<<dim3(4 * HH / 32, HH / 32, NLAYER), tb, 0, stream>>>(ff1_w, ff1T, HH, 4 * HH);
    conv_transpose<<<dim3(HH / 32, 4 * HH / 32, NLAYER), tb, 0, stream>>>(ff2_w, ff2T, 4 * HH, HH);
    conv_transpose<<<dim3(VV / 32, HH / 32, 1), tb, 0, stream>>>(pred_w, predT, HH, VV);

    embed_kernel<<<MROWS, 192, 0, stream>>>(ids, bpe, pos, h, hb);

    for (int l = 0; l < NLAYER; ++l) {
        mfma_gemm<0, 1, 0><<<dim3(3 * HH / 128, MROWS / 128), 256, 0, stream>>>(
            hb, qkvT + (size_t)l * HH * 3 * HH, qkv_b + (size_t)l * 3 * HH,
            qkv, nullptr, MROWS, 3 * HH, HH);
        attn_kernel<<<dim3(SS / 64, NHEAD, BB), 256, 0, stream>>>(qkv, seq_mask, avb);
        mfma_gemm<0, 1, 0><<<dim3(HH / 128, MROWS / 128), 256, 0, stream>>>(
            avb, resT + (size_t)l * HH * HH, res_b + (size_t)l * HH,
            a, nullptr, MROWS, HH, HH);
        add_ln_kernel<<<MROWS, 256, 0, stream>>>(h, hb, a,
            ln1_g + (size_t)l * HH, ln1_b + (size_t)l * HH);
        mfma_gemm<1, 0, 1><<<dim3(4 * HH / 128, MROWS / 128), 256, 0, stream>>>(
            hb, ff1T + (size_t)l * HH * 4 * HH, ff1_b + (size_t)l * 4 * HH,
            nullptr, midb, MROWS, 4 * HH, HH);
        mfma_gemm<0, 1, 0><<<dim3(HH / 128, MROWS / 128), 256, 0, stream>>>(
            midb, ff2T + (size_t)l * 4 * HH * HH, ff2_b + (size_t)l * HH,
            a, nullptr, MROWS, HH, 4 * HH);
        add_ln_kernel<<<MROWS, 256, 0, stream>>>(h, hb, a,
            ln2_g + (size_t)l * HH, ln2_b + (size_t)l * HH);
    }

    mfma_gemm<0, 1, 0><<<dim3(VV / 128, MROWS / 128), 256, 0, stream>>>(
        hb, predT, nullptr, out_score, nullptr, MROWS, VV, HH);
    softmax_v_kernel<<<MROWS, 256, 0, stream>>>(out_score, out_prob);
}

// Round 4
// 1288.593 us; speedup vs baseline: 15.6719x; 9.4898x over previous
//
#include <hip/hip_runtime.h>
#include <math.h>

#define BB 2
#define SS 1024
#define HH 768
#define NHEAD 12
#define HDIM 64
#define NLAYER 4
#define VV 32000
#define MROWS (BB*SS)

typedef unsigned short u16;
typedef __attribute__((ext_vector_type(8))) short short8;
typedef __attribute__((ext_vector_type(4))) float f32x4;
typedef __attribute__((ext_vector_type(4))) unsigned short u16x4;

__device__ __forceinline__ u16 f2bf(float f) {
    union { float f; unsigned u; } x; x.f = f;
    unsigned r = (x.u + 0x7fff + ((x.u >> 16) & 1)) >> 16;
    return (u16)r;
}

__device__ __forceinline__ short8 pack8(float4 a, float4 b) {
    short8 r;
    r[0]=(short)f2bf(a.x); r[1]=(short)f2bf(a.y); r[2]=(short)f2bf(a.z); r[3]=(short)f2bf(a.w);
    r[4]=(short)f2bf(b.x); r[5]=(short)f2bf(b.y); r[6]=(short)f2bf(b.z); r[7]=(short)f2bf(b.w);
    return r;
}

__device__ __forceinline__ void gload_lds16(const u16* g, u16* l) {
    __builtin_amdgcn_global_load_lds((const __attribute__((address_space(1))) void*)g,
                                     (__attribute__((address_space(3))) void*)l, 16, 0, 0);
}

// ---------------- weight convert + transpose: W[K][N] f32 -> Wt[N][K] bf16 ----
__global__ void conv_transpose(const float* __restrict__ W, u16* __restrict__ Wt,
                               int K, int N) {
    int l = blockIdx.z;
    W  += (size_t)l * K * N;
    Wt += (size_t)l * K * N;
    __shared__ u16 tile[32][33];
    int k0 = blockIdx.y * 32, n0 = blockIdx.x * 32;
    int tx = threadIdx.x, ty = threadIdx.y;   // 32 x 8
#pragma unroll
    for (int i = 0; i < 4; ++i)
        tile[ty + 8*i][tx] = f2bf(W[(size_t)(k0 + ty + 8*i) * N + n0 + tx]);
    __syncthreads();
#pragma unroll
    for (int i = 0; i < 4; ++i)
        Wt[(size_t)(n0 + ty + 8*i) * K + k0 + tx] = tile[tx][ty + 8*i];
}

// ---------------- embedding: h f32 + hb bf16 ----------------
__global__ void embed_kernel(const int* __restrict__ ids,
                             const float* __restrict__ bpe,
                             const float* __restrict__ pos,
                             float* __restrict__ h, u16* __restrict__ hb) {
    int row = blockIdx.x;
    int s = row % SS;
    int id = ids[row];
    const float4* br = (const float4*)(bpe + (size_t)id * HH);
    const float4* pr = (const float4*)(pos + (size_t)s * HH);
    float4* hr = (float4*)(h + (size_t)row * HH);
    u16x4* hbr = (u16x4*)(hb + (size_t)row * HH);
    int t = threadIdx.x;                  // 192 threads, 1 float4 each
    float4 a = br[t], c = pr[t];
    a.x += c.x; a.y += c.y; a.z += c.z; a.w += c.w;
    hr[t] = a;
    u16x4 u; u[0] = f2bf(a.x); u[1] = f2bf(a.y); u[2] = f2bf(a.z); u[3] = f2bf(a.w);
    hbr[t] = u;
}

// ---------------- MFMA GEMM: C[M][N] = A[M][K](bf16) * Wt[N][K](bf16)^T ------
template<int ACT, int WF32, int WBF>
__global__ __launch_bounds__(256) void mfma_gemm(
    const u16* __restrict__ A, const u16* __restrict__ Wt,
    const float* __restrict__ bias, float* __restrict__ C,
    u16* __restrict__ Cb, int M, int N, int K) {
    __shared__ u16 As[128 * 32];
    __shared__ u16 Bs[128 * 32];
    const int tid = threadIdx.x;
    const int lane = tid & 63;
    const int wid = tid >> 6;
    const int brow = blockIdx.y * 128;
    const int bcol = blockIdx.x * 128;
    const int wr = (wid >> 1) * 64;
    const int wc = (wid & 1) * 64;
    f32x4 acc[4][4] = {};

    const u16* Abase = A + (size_t)brow * K;
    const u16* Bbase = Wt + (size_t)bcol * K;
    const int lrow = lane & 15;
    const int lk = (lane >> 4) * 8;

    for (int kt = 0; kt < K; kt += 32) {
        __syncthreads();
#pragma unroll
        for (int i = 0; i < 2; ++i) {
            int c = tid + i * 256;
            int r = c >> 2;
            int off = (c & 3) * 8;
            gload_lds16(Abase + (size_t)r * K + kt + off, As + c * 8);
            gload_lds16(Bbase + (size_t)r * K + kt + off, Bs + c * 8);
        }
        __syncthreads();
        short8 a[4], b[4];
#pragma unroll
        for (int m = 0; m < 4; ++m)
            a[m] = *(const short8*)(As + (wr + m * 16 + lrow) * 32 + lk);
#pragma unroll
        for (int n = 0; n < 4; ++n)
            b[n] = *(const short8*)(Bs + (wc + n * 16 + lrow) * 32 + lk);
#pragma unroll
        for (int m = 0; m < 4; ++m)
#pragma unroll
            for (int n = 0; n < 4; ++n)
                acc[m][n] = __builtin_amdgcn_mfma_f32_16x16x32_bf16(a[m], b[n], acc[m][n], 0, 0, 0);
    }

    const int lr4 = (lane >> 4) * 4;
#pragma unroll
    for (int n = 0; n < 4; ++n) {
        int col = bcol + wc + n * 16 + lrow;
        float bv = bias ? bias[col] : 0.f;
#pragma unroll
        for (int m = 0; m < 4; ++m) {
#pragma unroll
            for (int j = 0; j < 4; ++j) {
                int row = brow + wr + m * 16 + lr4 + j;
                float v = acc[m][n][j] + bv;
                if (ACT == 1) v = 0.5f * v * (1.f + erff(v * 0.70710678118654752f));
                if (WF32) C[(size_t)row * N + col] = v;
                if (WBF)  Cb[(size_t)row * N + col] = f2bf(v);
            }
        }
    }
}

// ---------------- MFMA flash attention ----------------
// block = 64 q-rows of one (b,head); 4 waves; wave w owns q-rows [16w,16w+16).
// Fragment layouts identical to (verified) mfma_gemm:
//   A-frag: row=lane&15, k=(lane>>4)*8+e ; B-frag: col=lane&15, same k
//   C/D:    col=lane&15, row=(lane>>4)*4+j
// K tile [k][d] bf16 and V^T tile [d][k] bf16 in LDS, XOR-swizzled
// (byte ^= (row&7)<<4) to kill the 128B-row-stride bank conflict (G4).
// P strip written bf16 to LDS by each wave, read back as A-frags (wave-local).
__global__ __launch_bounds__(256) void attn_kernel(
    const float* __restrict__ qkv, const float* __restrict__ seq_mask,
    u16* __restrict__ av) {
    __shared__ u16 Ks[64 * 64];
    __shared__ u16 Vt[64 * 64];
    __shared__ u16 Ps[64 * 64];
    const int qb = blockIdx.x, hd = blockIdx.y, b = blockIdx.z;
    const int t = threadIdx.x;
    const int lane = t & 63;
    const int w = t >> 6;
    const int lrow = lane & 15;
    const int lhi = lane >> 4;
    const int q0 = qb * 64;
    const size_t rs = 3 * HH;

    // Q A-frags (stay in registers): row = q0+16w+lrow, k = c*32+lhi*8..+8
    short8 aq[2];
    {
        const float* qrow = qkv + (size_t)(b * SS + q0 + w * 16 + lrow) * rs + hd * HDIM;
#pragma unroll
        for (int c = 0; c < 2; ++c) {
            float4 f0 = *(const float4*)(qrow + c * 32 + lhi * 8);
            float4 f1 = *(const float4*)(qrow + c * 32 + lhi * 8 + 4);
            aq[c] = pack8(f0, f1);
        }
    }

    f32x4 o[4] = {};
    float m_[4] = {-INFINITY, -INFINITY, -INFINITY, -INFINITY};
    float l_[4] = {0.f, 0.f, 0.f, 0.f};

    for (int kt = 0; kt <= qb; ++kt) {
        const int k0 = kt * 64;
        __syncthreads();                       // prior tile's LDS reads done
        // ---- stage K[k][d] and V^T[d][k] (bf16, swizzled) ----
        {
            const int kr = t >> 2, dc = t & 3;
            const float* kbase = qkv + (size_t)(b * SS + k0 + kr) * rs + HH + hd * HDIM + dc * 16;
            float4 ka = *(const float4*)(kbase + 0);
            float4 kb = *(const float4*)(kbase + 4);
            float4 kc = *(const float4*)(kbase + 8);
            float4 kd = *(const float4*)(kbase + 12);
            char* krowp = (char*)Ks + kr * 128;
            *(short8*)(krowp + (((dc * 32 + 0)  ^ ((kr & 7) << 4)))) = pack8(ka, kb);
            *(short8*)(krowp + (((dc * 32 + 16) ^ ((kr & 7) << 4)))) = pack8(kc, kd);

            const float* vbase = kbase + HH;   // V part
            float4 va = *(const float4*)(vbase + 0);
            float4 vb = *(const float4*)(vbase + 4);
            float4 vc = *(const float4*)(vbase + 8);
            float4 vd = *(const float4*)(vbase + 12);
            u16 vh[16];
            vh[0]=f2bf(va.x); vh[1]=f2bf(va.y); vh[2]=f2bf(va.z); vh[3]=f2bf(va.w);
            vh[4]=f2bf(vb.x); vh[5]=f2bf(vb.y); vh[6]=f2bf(vb.z); vh[7]=f2bf(vb.w);
            vh[8]=f2bf(vc.x); vh[9]=f2bf(vc.y); vh[10]=f2bf(vc.z); vh[11]=f2bf(vc.w);
            vh[12]=f2bf(vd.x); vh[13]=f2bf(vd.y); vh[14]=f2bf(vd.z); vh[15]=f2bf(vd.w);
#pragma unroll
            for (int e = 0; e < 16; ++e) {
                int d = dc * 16 + e;           // Vt row = d, col = kr
                *(u16*)((char*)Vt + d * 128 + ((kr * 2) ^ ((d & 7) << 4))) = vh[e];
            }
        }
        __syncthreads();

        // ---- S = Q K^T : 4 col-frags x 2 k-chunks ----
        f32x4 s[4] = {};
#pragma unroll
        for (int n = 0; n < 4; ++n) {
            const int krow = n * 16 + lrow;    // B-frag row = k col index
            char* kp = (char*)Ks + krow * 128;
#pragma unroll
            for (int c = 0; c < 2; ++c) {
                short8 bk = *(const short8*)(kp + ((c * 64 + lhi * 16) ^ ((krow & 7) << 4)));
                s[n] = __builtin_amdgcn_mfma_f32_16x16x32_bf16(aq[c], bk, s[n], 0, 0, 0);
            }
        }

        // ---- online softmax (rows rr*4+j owned by 16-lane group) ----
        float sm[4];
#pragma unroll
        for (int n = 0; n < 4; ++n) sm[n] = seq_mask[b * SS + k0 + n * 16 + lrow];
        const int diag = (kt == qb);
#pragma unroll
        for (int j = 0; j < 4; ++j) {
            const int qglob = q0 + w * 16 + lhi * 4 + j;
            float sv[4];
#pragma unroll
            for (int n = 0; n < 4; ++n) {
                const int kglob = k0 + n * 16 + lrow;
                float msk = (diag && kglob > qglob) ? 0.f : sm[n];
                sv[n] = s[n][j] * 0.125f + (1.f - msk) * (-1e9f);
            }
            float tm = fmaxf(fmaxf(sv[0], sv[1]), fmaxf(sv[2], sv[3]));
            tm = fmaxf(tm, __shfl_xor(tm, 1));
            tm = fmaxf(tm, __shfl_xor(tm, 2));
            tm = fmaxf(tm, __shfl_xor(tm, 4));
            tm = fmaxf(tm, __shfl_xor(tm, 8));
            float mn = fmaxf(m_[j], tm);
            float sc = __expf(m_[j] - mn);     // first tile: exp(-inf)=0
            float ps = 0.f;
#pragma unroll
            for (int n = 0; n < 4; ++n) {
                float p = __expf(sv[n] - mn);
                s[n][j] = p;
                ps += p;
            }
            ps += __shfl_xor(ps, 1);
            ps += __shfl_xor(ps, 2);
            ps += __shfl_xor(ps, 4);
            ps += __shfl_xor(ps, 8);
            l_[j] = l_[j] * sc + ps;
            m_[j] = mn;
#pragma unroll
            for (int dn = 0; dn < 4; ++dn) o[dn][j] *= sc;
        }

        // ---- P -> LDS (bf16, swizzled); wave-local strip ----
#pragma unroll
        for (int j = 0; j < 4; ++j) {
            const int prow = w * 16 + lhi * 4 + j;
            char* pp = (char*)Ps + prow * 128;
#pragma unroll
            for (int n = 0; n < 4; ++n)
                *(u16*)(pp + ((n * 32 + lrow * 2) ^ ((prow & 7) << 4))) = f2bf(s[n][j]);
        }

        // ---- PV: O += P * V^T ----
        const int arow = w * 16 + lrow;
        char* ap_p = (char*)Ps + arow * 128;
#pragma unroll
        for (int c = 0; c < 2; ++c) {
            short8 ap = *(const short8*)(ap_p + ((c * 64 + lhi * 16) ^ ((arow & 7) << 4)));
#pragma unroll
            for (int dn = 0; dn < 4; ++dn) {
                const int vrow = dn * 16 + lrow;
                short8 bv = *(const short8*)((char*)Vt + vrow * 128 +
                                             ((c * 64 + lhi * 16) ^ ((vrow & 7) << 4)));
                o[dn] = __builtin_amdgcn_mfma_f32_16x16x32_bf16(ap, bv, o[dn], 0, 0, 0);
            }
        }
    }

    // ---- epilogue: normalize + store bf16 ----
#pragma unroll
    for (int j = 0; j < 4; ++j) {
        const int q = q0 + w * 16 + lhi * 4 + j;
        const float inv = 1.f / l_[j];
        u16* orow = av + (size_t)(b * SS + q) * HH + hd * HDIM;
#pragma unroll
        for (int dn = 0; dn < 4; ++dn)
            orow[dn * 16 + lrow] = f2bf(o[dn][j] * inv);
    }
}

// ---------------- residual add + layernorm: h f32 + hb bf16 ----------------
__global__ void add_ln_kernel(float* __restrict__ h, u16* __restrict__ hb,
                              const float* __restrict__ a,
                              const float* __restrict__ g,
                              const float* __restrict__ bta) {
    int row = blockIdx.x;
    int t = threadIdx.x;
    __shared__ float red[256];
    size_t base = (size_t)row * HH;
    float x0 = h[base + t]       + a[base + t];
    float x1 = h[base + t + 256] + a[base + t + 256];
    float x2 = h[base + t + 512] + a[base + t + 512];

    red[t] = x0 + x1 + x2;
    __syncthreads();
    for (int o = 128; o; o >>= 1) { if (t < o) red[t] += red[t + o]; __syncthreads(); }
    float mean = red[0] * (1.0f / 768.0f);
    __syncthreads();

    float d0 = x0 - mean, d1 = x1 - mean, d2 = x2 - mean;
    red[t] = d0 * d0 + d1 * d1 + d2 * d2;
    __syncthreads();
    for (int o = 128; o; o >>= 1) { if (t < o) red[t] += red[t + o]; __syncthreads(); }
    float var = red[0] * (1.0f / 768.0f);
    float inv = 1.0f / sqrtf(var + 1e-5f);

    float y0 = g[t]       * d0 * inv + bta[t];
    float y1 = g[t + 256] * d1 * inv + bta[t + 256];
    float y2 = g[t + 512] * d2 * inv + bta[t + 512];
    h[base + t] = y0;       hb[base + t] = f2bf(y0);
    h[base + t + 256] = y1; hb[base + t + 256] = f2bf(y1);
    h[base + t + 512] = y2; hb[base + t + 512] = f2bf(y2);
}

// ---------------- row softmax over V=32000 (float4) ----------------
__global__ void softmax_v_kernel(const float* __restrict__ score,
                                 float* __restrict__ prob) {
    int row = blockIdx.x;
    int t = threadIdx.x;
    __shared__ float red[256];
    const float4* sr = (const float4*)(score + (size_t)row * VV);
    float4* pr = (float4*)(prob + (size_t)row * VV);
    const int n4 = VV / 4;

    float mx = -INFINITY;
    for (int i = t; i < n4; i += 256) {
        float4 v = sr[i];
        mx = fmaxf(mx, fmaxf(fmaxf(v.x, v.y), fmaxf(v.z, v.w)));
    }
    red[t] = mx; __syncthreads();
    for (int o = 128; o; o >>= 1) { if (t < o) red[t] = fmaxf(red[t], red[t + o]); __syncthreads(); }
    mx = red[0];
    __syncthreads();

    float s = 0.f;
    for (int i = t; i < n4; i += 256) {
        float4 v = sr[i];
        s += expf(v.x - mx) + expf(v.y - mx) + expf(v.z - mx) + expf(v.w - mx);
    }
    red[t] = s; __syncthreads();
    for (int o = 128; o; o >>= 1) { if (t < o) red[t] += red[t + o]; __syncthreads(); }
    float inv = 1.0f / red[0];

    for (int i = t; i < n4; i += 256) {
        float4 v = sr[i];
        float4 o4;
        o4.x = expf(v.x - mx) * inv; o4.y = expf(v.y - mx) * inv;
        o4.z = expf(v.z - mx) * inv; o4.w = expf(v.w - mx) * inv;
        pr[i] = o4;
    }
}

extern "C" void kernel_launch(void* const* d_in, const int* in_sizes, int n_in,
                              void* d_out, int out_size, void* d_ws, size_t ws_size,
                              hipStream_t stream) {
    const int*   ids      = (const int*)d_in[0];
    const float* seq_mask = (const float*)d_in[1];
    const float* bpe      = (const float*)d_in[2];
    const float* pos      = (const float*)d_in[3];
    const float* qkv_w    = (const float*)d_in[4];
    const float* qkv_b    = (const float*)d_in[5];
    const float* res_w    = (const float*)d_in[6];
    const float* res_b    = (const float*)d_in[7];
    const float* ln1_g    = (const float*)d_in[8];
    const float* ln1_b    = (const float*)d_in[9];
    const float* ff1_w    = (const float*)d_in[10];
    const float* ff1_b    = (const float*)d_in[11];
    const float* ff2_w    = (const float*)d_in[12];
    const float* ff2_b    = (const float*)d_in[13];
    const float* ln2_g    = (const float*)d_in[14];
    const float* ln2_b    = (const float*)d_in[15];
    const float* pred_w   = (const float*)d_in[16];

    float* out_score = (float*)d_out;
    float* out_prob  = out_score + (size_t)MROWS * VV;

    // arena layout
    size_t off = 0;
    auto take = [&](size_t bytes) -> size_t {
        size_t p = off; off += (bytes + 255) & ~(size_t)255; return p;
    };
    const size_t o_qkvT = take((size_t)NLAYER * HH * 3 * HH * 2);
    const size_t o_resT = take((size_t)NLAYER * HH * HH * 2);
    const size_t o_ff1T = take((size_t)NLAYER * HH * 4 * HH * 2);
    const size_t o_ff2T = take((size_t)NLAYER * 4 * HH * HH * 2);
    const size_t o_predT = take((size_t)HH * VV * 2);
    const size_t o_h    = take((size_t)MROWS * HH * 4);
    const size_t o_a    = take((size_t)MROWS * HH * 4);
    const size_t o_qkv  = take((size_t)MROWS * 3 * HH * 4);
    const size_t o_hb   = take((size_t)MROWS * HH * 2);
    const size_t o_avb  = take((size_t)MROWS * HH * 2);
    const size_t o_midb = take((size_t)MROWS * 4 * HH * 2);
    const size_t need = off;

    char* arena = (ws_size >= need) ? (char*)d_ws : (char*)out_prob;
    u16*   qkvT = (u16*)(arena + o_qkvT);
    u16*   resT = (u16*)(arena + o_resT);
    u16*   ff1T = (u16*)(arena + o_ff1T);
    u16*   ff2T = (u16*)(arena + o_ff2T);
    u16*   predT = (u16*)(arena + o_predT);
    float* h    = (float*)(arena + o_h);
    float* a    = (float*)(arena + o_a);
    float* qkv  = (float*)(arena + o_qkv);
    u16*   hb   = (u16*)(arena + o_hb);
    u16*   avb  = (u16*)(arena + o_avb);
    u16*   midb = (u16*)(arena + o_midb);

    dim3 tb(32, 8);
    conv_transpose<<<dim3(3 * HH / 32, HH / 32, NLAYER), tb, 0, stream>>>(qkv_w, qkvT, HH, 3 * HH);
    conv_transpose<<<dim3(HH / 32, HH / 32, NLAYER), tb, 0, stream>>>(res_w, resT, HH, HH);
    conv_transpose<<<dim3(4 * HH / 32, HH / 32, NLAYER), tb, 0, stream>>>(ff1_w, ff1T, HH, 4 * HH);
    conv_transpose<<<dim3(HH / 32, 4 * HH / 32, NLAYER), tb, 0, stream>>>(ff2_w, ff2T, 4 * HH, HH);
    conv_transpose<<<dim3(VV / 32, HH / 32, 1), tb, 0, stream>>>(pred_w, predT, HH, VV);

    embed_kernel<<<MROWS, 192, 0, stream>>>(ids, bpe, pos, h, hb);

    for (int l = 0; l < NLAYER; ++l) {
        mfma_gemm<0, 1, 0><<<dim3(3 * HH / 128, MROWS / 128), 256, 0, stream>>>(
            hb, qkvT + (size_t)l * HH * 3 * HH, qkv_b + (size_t)l * 3 * HH,
            qkv, nullptr, MROWS, 3 * HH, HH);
        attn_kernel<<<dim3(SS / 64, NHEAD, BB), 256, 0, stream>>>(qkv, seq_mask, avb);
        mfma_gemm<0, 1, 0><<<dim3(HH / 128, MROWS / 128), 256, 0, stream>>>(
            avb, resT + (size_t)l * HH * HH, res_b + (size_t)l * HH,
            a, nullptr, MROWS, HH, HH);
        add_ln_kernel<<<MROWS, 256, 0, stream>>>(h, hb, a,
            ln1_g + (size_t)l * HH, ln1_b + (size_t)l * HH);
        mfma_gemm<1, 0, 1><<<dim3(4 * HH / 128, MROWS / 128), 256, 0, stream>>>(
            hb, ff1T + (size_t)l * HH * 4 * HH, ff1_b + (size_t)l * 4 * HH,
            nullptr, midb, MROWS, 4 * HH, HH);
        mfma_gemm<0, 1, 0><<<dim3(HH / 128, MROWS / 128), 256, 0, stream>>>(
            midb, ff2T + (size_t)l * 4 * HH * HH, ff2_b + (size_t)l * HH,
            a, nullptr, MROWS, HH, 4 * HH);
        add_ln_kernel<<<MROWS, 256, 0, stream>>>(h, hb, a,
            ln2_g + (size_t)l * HH, ln2_b + (size_t)l * HH);
    }

    mfma_gemm<0, 1, 0><<<dim3(VV / 128, MROWS / 128), 256, 0, stream>>>(
        hb, predT, nullptr, out_score, nullptr, MROWS, VV, HH);
    softmax_v_kernel<<<MROWS, 256, 0, stream>>>(out_score, out_prob);
}

// Round 5
// 1230.718 us; speedup vs baseline: 16.4089x; 1.0470x over previous
//
#include <hip/hip_runtime.h>
#include <math.h>

#define BB 2
#define SS 1024
#define HH 768
#define NHEAD 12
#define HDIM 64
#define NLAYER 4
#define VV 32000
#define MROWS (BB*SS)

typedef unsigned short u16;
typedef __attribute__((ext_vector_type(8))) short short8;
typedef __attribute__((ext_vector_type(4))) float f32x4;
typedef __attribute__((ext_vector_type(4))) unsigned short u16x4;

__device__ __forceinline__ u16 f2bf(float f) {
    union { float f; unsigned u; } x; x.f = f;
    unsigned r = (x.u + 0x7fff + ((x.u >> 16) & 1)) >> 16;
    return (u16)r;
}
__device__ __forceinline__ float bf2f(u16 b) {
    union { unsigned u; float f; } x; x.u = ((unsigned)b) << 16;
    return x.f;
}

__device__ __forceinline__ void gload_lds16(const u16* g, u16* l) {
    __builtin_amdgcn_global_load_lds((const __attribute__((address_space(1))) void*)g,
                                     (__attribute__((address_space(3))) void*)l, 16, 0, 0);
}

// ---------------- weight convert + transpose: W[K][N] f32 -> Wt[N][K] bf16 ----
__global__ void conv_transpose(const float* __restrict__ W, u16* __restrict__ Wt,
                               int K, int N) {
    int l = blockIdx.z;
    W  += (size_t)l * K * N;
    Wt += (size_t)l * K * N;
    __shared__ u16 tile[32][33];
    int k0 = blockIdx.y * 32, n0 = blockIdx.x * 32;
    int tx = threadIdx.x, ty = threadIdx.y;   // 32 x 8
#pragma unroll
    for (int i = 0; i < 4; ++i)
        tile[ty + 8*i][tx] = f2bf(W[(size_t)(k0 + ty + 8*i) * N + n0 + tx]);
    __syncthreads();
#pragma unroll
    for (int i = 0; i < 4; ++i)
        Wt[(size_t)(n0 + ty + 8*i) * K + k0 + tx] = tile[tx][ty + 8*i];
}

// ---------------- embedding: h f32 + hb bf16 ----------------
__global__ void embed_kernel(const int* __restrict__ ids,
                             const float* __restrict__ bpe,
                             const float* __restrict__ pos,
                             float* __restrict__ h, u16* __restrict__ hb) {
    int row = blockIdx.x;
    int s = row % SS;
    int id = ids[row];
    const float4* br = (const float4*)(bpe + (size_t)id * HH);
    const float4* pr = (const float4*)(pos + (size_t)s * HH);
    float4* hr = (float4*)(h + (size_t)row * HH);
    u16x4* hbr = (u16x4*)(hb + (size_t)row * HH);
    int t = threadIdx.x;                  // 192 threads, 1 float4 each
    float4 a = br[t], c = pr[t];
    a.x += c.x; a.y += c.y; a.z += c.z; a.w += c.w;
    hr[t] = a;
    u16x4 u; u[0] = f2bf(a.x); u[1] = f2bf(a.y); u[2] = f2bf(a.z); u[3] = f2bf(a.w);
    hbr[t] = u;
}

// ---------------- MFMA GEMM: C[M][N] = A[M][K](bf16) * Wt[N][K](bf16)^T ------
// Grid: x = M-tile (fast-varying), y = N-tile -> consecutive blocks share the
// B panel (196KB, L2-resident) and sweep A (3MB, L2-resident). B fetched once.
template<int ACT, int WF32, int WBF>
__global__ __launch_bounds__(256) void mfma_gemm(
    const u16* __restrict__ A, const u16* __restrict__ Wt,
    const float* __restrict__ bias, float* __restrict__ C,
    u16* __restrict__ Cb, int M, int N, int K) {
    __shared__ u16 As[128 * 32];
    __shared__ u16 Bs[128 * 32];
    const int tid = threadIdx.x;
    const int lane = tid & 63;
    const int wid = tid >> 6;
    const int brow = blockIdx.x * 128;
    const int bcol = blockIdx.y * 128;
    const int wr = (wid >> 1) * 64;
    const int wc = (wid & 1) * 64;
    f32x4 acc[4][4] = {};

    const u16* Abase = A + (size_t)brow * K;
    const u16* Bbase = Wt + (size_t)bcol * K;
    const int lrow = lane & 15;
    const int lk = (lane >> 4) * 8;

    for (int kt = 0; kt < K; kt += 32) {
        __syncthreads();
#pragma unroll
        for (int i = 0; i < 2; ++i) {
            int c = tid + i * 256;
            int r = c >> 2;
            int off = (c & 3) * 8;
            gload_lds16(Abase + (size_t)r * K + kt + off, As + c * 8);
            gload_lds16(Bbase + (size_t)r * K + kt + off, Bs + c * 8);
        }
        __syncthreads();
        short8 a[4], b[4];
#pragma unroll
        for (int m = 0; m < 4; ++m)
            a[m] = *(const short8*)(As + (wr + m * 16 + lrow) * 32 + lk);
#pragma unroll
        for (int n = 0; n < 4; ++n)
            b[n] = *(const short8*)(Bs + (wc + n * 16 + lrow) * 32 + lk);
#pragma unroll
        for (int m = 0; m < 4; ++m)
#pragma unroll
            for (int n = 0; n < 4; ++n)
                acc[m][n] = __builtin_amdgcn_mfma_f32_16x16x32_bf16(a[m], b[n], acc[m][n], 0, 0, 0);
    }

    const int lr4 = (lane >> 4) * 4;
#pragma unroll
    for (int n = 0; n < 4; ++n) {
        int col = bcol + wc + n * 16 + lrow;
        float bv = bias ? bias[col] : 0.f;
#pragma unroll
        for (int m = 0; m < 4; ++m) {
#pragma unroll
            for (int j = 0; j < 4; ++j) {
                int row = brow + wr + m * 16 + lr4 + j;
                float v = acc[m][n][j] + bv;
                if (ACT == 1) v = 0.5f * v * (1.f + erff(v * 0.70710678118654752f));
                if (WF32) C[(size_t)row * N + col] = v;
                if (WBF)  Cb[(size_t)row * N + col] = f2bf(v);
            }
        }
    }
}

// ---------------- MFMA flash attention (bf16 QKV input) ----------------
// block = 64 q-rows of one (b,head); 4 waves; wave w owns q-rows [16w,16w+16).
// K tile [k][d] and V^T tile [d][k] bf16 in LDS, XOR-swizzled (byte^=(row&7)<<4).
__global__ __launch_bounds__(256) void attn_kernel(
    const u16* __restrict__ qkvb, const float* __restrict__ seq_mask,
    u16* __restrict__ av) {
    __shared__ u16 Ks[64 * 64];
    __shared__ u16 Vt[64 * 64];
    __shared__ u16 Ps[64 * 64];
    const int qb = blockIdx.x, hd = blockIdx.y, b = blockIdx.z;
    const int t = threadIdx.x;
    const int lane = t & 63;
    const int w = t >> 6;
    const int lrow = lane & 15;
    const int lhi = lane >> 4;
    const int q0 = qb * 64;
    const size_t rs = 3 * HH;

    // Q A-frags straight from bf16 global: row = q0+16w+lrow, k = c*32+lhi*8..+8
    short8 aq[2];
    {
        const u16* qrow = qkvb + (size_t)(b * SS + q0 + w * 16 + lrow) * rs + hd * HDIM;
        aq[0] = *(const short8*)(qrow + lhi * 8);
        aq[1] = *(const short8*)(qrow + 32 + lhi * 8);
    }

    f32x4 o[4] = {};
    float m_[4] = {-INFINITY, -INFINITY, -INFINITY, -INFINITY};
    float l_[4] = {0.f, 0.f, 0.f, 0.f};

    for (int kt = 0; kt <= qb; ++kt) {
        const int k0 = kt * 64;
        __syncthreads();                       // prior tile's LDS reads done
        // ---- stage K[k][d] and V^T[d][k] (pure u16 copies, swizzled) ----
        {
            const int kr = t >> 2, dc = t & 3;
            const u16* kbase = qkvb + (size_t)(b * SS + k0 + kr) * rs + HH + hd * HDIM + dc * 16;
            short8 kA = *(const short8*)(kbase);
            short8 kB = *(const short8*)(kbase + 8);
            char* krowp = (char*)Ks + kr * 128;
            *(short8*)(krowp + (((dc * 32 + 0)  ^ ((kr & 7) << 4)))) = kA;
            *(short8*)(krowp + (((dc * 32 + 16) ^ ((kr & 7) << 4)))) = kB;

            const u16* vbase = kbase + HH;     // V part
            short8 vA = *(const short8*)(vbase);
            short8 vB = *(const short8*)(vbase + 8);
#pragma unroll
            for (int e = 0; e < 8; ++e) {
                int d0 = dc * 16 + e;
                int d1 = dc * 16 + 8 + e;
                *(u16*)((char*)Vt + d0 * 128 + ((kr * 2) ^ ((d0 & 7) << 4))) = (u16)vA[e];
                *(u16*)((char*)Vt + d1 * 128 + ((kr * 2) ^ ((d1 & 7) << 4))) = (u16)vB[e];
            }
        }
        __syncthreads();

        // ---- S = Q K^T ----
        f32x4 s[4] = {};
        __builtin_amdgcn_s_setprio(1);
#pragma unroll
        for (int n = 0; n < 4; ++n) {
            const int krow = n * 16 + lrow;    // B-frag row = k col index
            char* kp = (char*)Ks + krow * 128;
#pragma unroll
            for (int c = 0; c < 2; ++c) {
                short8 bk = *(const short8*)(kp + ((c * 64 + lhi * 16) ^ ((krow & 7) << 4)));
                s[n] = __builtin_amdgcn_mfma_f32_16x16x32_bf16(aq[c], bk, s[n], 0, 0, 0);
            }
        }
        __builtin_amdgcn_s_setprio(0);

        // ---- online softmax (rows lhi*4+j owned by 16-lane group) ----
        float sm[4];
#pragma unroll
        for (int n = 0; n < 4; ++n) sm[n] = seq_mask[b * SS + k0 + n * 16 + lrow];
        const int diag = (kt == qb);
#pragma unroll
        for (int j = 0; j < 4; ++j) {
            const int qglob = q0 + w * 16 + lhi * 4 + j;
            float sv[4];
#pragma unroll
            for (int n = 0; n < 4; ++n) {
                const int kglob = k0 + n * 16 + lrow;
                float msk = (diag && kglob > qglob) ? 0.f : sm[n];
                sv[n] = s[n][j] * 0.125f + (1.f - msk) * (-1e9f);
            }
            float tm = fmaxf(fmaxf(sv[0], sv[1]), fmaxf(sv[2], sv[3]));
            tm = fmaxf(tm, __shfl_xor(tm, 1));
            tm = fmaxf(tm, __shfl_xor(tm, 2));
            tm = fmaxf(tm, __shfl_xor(tm, 4));
            tm = fmaxf(tm, __shfl_xor(tm, 8));
            float mn = fmaxf(m_[j], tm);
            float sc = __expf(m_[j] - mn);     // first tile: exp(-inf)=0
            float ps = 0.f;
#pragma unroll
            for (int n = 0; n < 4; ++n) {
                float p = __expf(sv[n] - mn);
                s[n][j] = p;
                ps += p;
            }
            ps += __shfl_xor(ps, 1);
            ps += __shfl_xor(ps, 2);
            ps += __shfl_xor(ps, 4);
            ps += __shfl_xor(ps, 8);
            l_[j] = l_[j] * sc + ps;
            m_[j] = mn;
#pragma unroll
            for (int dn = 0; dn < 4; ++dn) o[dn][j] *= sc;
        }

        // ---- P -> LDS (bf16, swizzled); wave-local strip ----
#pragma unroll
        for (int j = 0; j < 4; ++j) {
            const int prow = w * 16 + lhi * 4 + j;
            char* pp = (char*)Ps + prow * 128;
#pragma unroll
            for (int n = 0; n < 4; ++n)
                *(u16*)(pp + ((n * 32 + lrow * 2) ^ ((prow & 7) << 4))) = f2bf(s[n][j]);
        }

        // ---- PV: O += P * V^T ----
        const int arow = w * 16 + lrow;
        char* ap_p = (char*)Ps + arow * 128;
        __builtin_amdgcn_s_setprio(1);
#pragma unroll
        for (int c = 0; c < 2; ++c) {
            short8 ap = *(const short8*)(ap_p + ((c * 64 + lhi * 16) ^ ((arow & 7) << 4)));
#pragma unroll
            for (int dn = 0; dn < 4; ++dn) {
                const int vrow = dn * 16 + lrow;
                short8 bv = *(const short8*)((char*)Vt + vrow * 128 +
                                             ((c * 64 + lhi * 16) ^ ((vrow & 7) << 4)));
                o[dn] = __builtin_amdgcn_mfma_f32_16x16x32_bf16(ap, bv, o[dn], 0, 0, 0);
            }
        }
        __builtin_amdgcn_s_setprio(0);
    }

    // ---- epilogue: normalize + store bf16 ----
#pragma unroll
    for (int j = 0; j < 4; ++j) {
        const int q = q0 + w * 16 + lhi * 4 + j;
        const float inv = 1.f / l_[j];
        u16* orow = av + (size_t)(b * SS + q) * HH + hd * HDIM;
#pragma unroll
        for (int dn = 0; dn < 4; ++dn)
            orow[dn * 16 + lrow] = f2bf(o[dn][j] * inv);
    }
}

// ---------------- residual add + layernorm: h f32 + hb bf16 ----------------
__global__ void add_ln_kernel(float* __restrict__ h, u16* __restrict__ hb,
                              const float* __restrict__ a,
                              const float* __restrict__ g,
                              const float* __restrict__ bta) {
    int row = blockIdx.x;
    int t = threadIdx.x;
    __shared__ float red[256];
    size_t base = (size_t)row * HH;
    float x0 = h[base + t]       + a[base + t];
    float x1 = h[base + t + 256] + a[base + t + 256];
    float x2 = h[base + t + 512] + a[base + t + 512];

    red[t] = x0 + x1 + x2;
    __syncthreads();
    for (int o = 128; o; o >>= 1) { if (t < o) red[t] += red[t + o]; __syncthreads(); }
    float mean = red[0] * (1.0f / 768.0f);
    __syncthreads();

    float d0 = x0 - mean, d1 = x1 - mean, d2 = x2 - mean;
    red[t] = d0 * d0 + d1 * d1 + d2 * d2;
    __syncthreads();
    for (int o = 128; o; o >>= 1) { if (t < o) red[t] += red[t + o]; __syncthreads(); }
    float var = red[0] * (1.0f / 768.0f);
    float inv = 1.0f / sqrtf(var + 1e-5f);

    float y0 = g[t]       * d0 * inv + bta[t];
    float y1 = g[t + 256] * d1 * inv + bta[t + 256];
    float y2 = g[t + 512] * d2 * inv + bta[t + 512];
    h[base + t] = y0;       hb[base + t] = f2bf(y0);
    h[base + t + 256] = y1; hb[base + t + 256] = f2bf(y1);
    h[base + t + 512] = y2; hb[base + t + 512] = f2bf(y2);
}

// ---------------- single-pass row softmax over V=32000 ----------------
// Score row staged bf16 in LDS (62.5KB): 1 HBM read + 1 HBM write.
__global__ __launch_bounds__(256) void softmax_v_kernel(
    const float* __restrict__ score, float* __restrict__ prob) {
    __shared__ u16 srow[VV];        // 64000 B
    __shared__ float red[256];
    int row = blockIdx.x;
    int t = threadIdx.x;
    const float4* sr = (const float4*)(score + (size_t)row * VV);
    float4* pr = (float4*)(prob + (size_t)row * VV);
    const int n4 = VV / 4;          // 8000

    float mx = -INFINITY;
    for (int i = t; i < n4; i += 256) {
        float4 v = sr[i];
        u16x4 u; u[0] = f2bf(v.x); u[1] = f2bf(v.y); u[2] = f2bf(v.z); u[3] = f2bf(v.w);
        *(u16x4*)(srow + i * 4) = u;
        mx = fmaxf(mx, fmaxf(fmaxf(bf2f(u[0]), bf2f(u[1])), fmaxf(bf2f(u[2]), bf2f(u[3]))));
    }
    red[t] = mx; __syncthreads();
    for (int o = 128; o; o >>= 1) { if (t < o) red[t] = fmaxf(red[t], red[t + o]); __syncthreads(); }
    mx = red[0];
    __syncthreads();

    float s = 0.f;
    for (int i = t; i < n4; i += 256) {
        u16x4 u = *(const u16x4*)(srow + i * 4);
        s += __expf(bf2f(u[0]) - mx) + __expf(bf2f(u[1]) - mx)
           + __expf(bf2f(u[2]) - mx) + __expf(bf2f(u[3]) - mx);
    }
    red[t] = s; __syncthreads();
    for (int o = 128; o; o >>= 1) { if (t < o) red[t] += red[t + o]; __syncthreads(); }
    float inv = 1.0f / red[0];

    for (int i = t; i < n4; i += 256) {
        u16x4 u = *(const u16x4*)(srow + i * 4);
        float4 o4;
        o4.x = __expf(bf2f(u[0]) - mx) * inv; o4.y = __expf(bf2f(u[1]) - mx) * inv;
        o4.z = __expf(bf2f(u[2]) - mx) * inv; o4.w = __expf(bf2f(u[3]) - mx) * inv;
        pr[i] = o4;
    }
}

extern "C" void kernel_launch(void* const* d_in, const int* in_sizes, int n_in,
                              void* d_out, int out_size, void* d_ws, size_t ws_size,
                              hipStream_t stream) {
    const int*   ids      = (const int*)d_in[0];
    const float* seq_mask = (const float*)d_in[1];
    const float* bpe      = (const float*)d_in[2];
    const float* pos      = (const float*)d_in[3];
    const float* qkv_w    = (const float*)d_in[4];
    const float* qkv_b    = (const float*)d_in[5];
    const float* res_w    = (const float*)d_in[6];
    const float* res_b    = (const float*)d_in[7];
    const float* ln1_g    = (const float*)d_in[8];
    const float* ln1_b    = (const float*)d_in[9];
    const float* ff1_w    = (const float*)d_in[10];
    const float* ff1_b    = (const float*)d_in[11];
    const float* ff2_w    = (const float*)d_in[12];
    const float* ff2_b    = (const float*)d_in[13];
    const float* ln2_g    = (const float*)d_in[14];
    const float* ln2_b    = (const float*)d_in[15];
    const float* pred_w   = (const float*)d_in[16];

    float* out_score = (float*)d_out;
    float* out_prob  = out_score + (size_t)MROWS * VV;

    // arena layout
    size_t off = 0;
    auto take = [&](size_t bytes) -> size_t {
        size_t p = off; off += (bytes + 255) & ~(size_t)255; return p;
    };
    const size_t o_qkvT = take((size_t)NLAYER * HH * 3 * HH * 2);
    const size_t o_resT = take((size_t)NLAYER * HH * HH * 2);
    const size_t o_ff1T = take((size_t)NLAYER * HH * 4 * HH * 2);
    const size_t o_ff2T = take((size_t)NLAYER * 4 * HH * HH * 2);
    const size_t o_predT = take((size_t)HH * VV * 2);
    const size_t o_h    = take((size_t)MROWS * HH * 4);
    const size_t o_a    = take((size_t)MROWS * HH * 4);
    const size_t o_qkvb = take((size_t)MROWS * 3 * HH * 2);
    const size_t o_hb   = take((size_t)MROWS * HH * 2);
    const size_t o_avb  = take((size_t)MROWS * HH * 2);
    const size_t o_midb = take((size_t)MROWS * 4 * HH * 2);
    const size_t need = off;

    char* arena = (ws_size >= need) ? (char*)d_ws : (char*)out_prob;
    u16*   qkvT = (u16*)(arena + o_qkvT);
    u16*   resT = (u16*)(arena + o_resT);
    u16*   ff1T = (u16*)(arena + o_ff1T);
    u16*   ff2T = (u16*)(arena + o_ff2T);
    u16*   predT = (u16*)(arena + o_predT);
    float* h    = (float*)(arena + o_h);
    float* a    = (float*)(arena + o_a);
    u16*   qkvb = (u16*)(arena + o_qkvb);
    u16*   hb   = (u16*)(arena + o_hb);
    u16*   avb  = (u16*)(arena + o_avb);
    u16*   midb = (u16*)(arena + o_midb);

    dim3 tb(32, 8);
    conv_transpose<<<dim3(3 * HH / 32, HH / 32, NLAYER), tb, 0, stream>>>(qkv_w, qkvT, HH, 3 * HH);
    conv_transpose<<<dim3(HH / 32, HH / 32, NLAYER), tb, 0, stream>>>(res_w, resT, HH, HH);
    conv_transpose<<<dim3(4 * HH / 32, HH / 32, NLAYER), tb, 0, stream>>>(ff1_w, ff1T, HH, 4 * HH);
    conv_transpose<<<dim3(HH / 32, 4 * HH / 32, NLAYER), tb, 0, stream>>>(ff2_w, ff2T, 4 * HH, HH);
    conv_transpose<<<dim3(VV / 32, HH / 32, 1), tb, 0, stream>>>(pred_w, predT, HH, VV);

    embed_kernel<<<MROWS, 192, 0, stream>>>(ids, bpe, pos, h, hb);

    for (int l = 0; l < NLAYER; ++l) {
        mfma_gemm<0, 0, 1><<<dim3(MROWS / 128, 3 * HH / 128), 256, 0, stream>>>(
            hb, qkvT + (size_t)l * HH * 3 * HH, qkv_b + (size_t)l * 3 * HH,
            nullptr, qkvb, MROWS, 3 * HH, HH);
        attn_kernel<<<dim3(SS / 64, NHEAD, BB), 256, 0, stream>>>(qkvb, seq_mask, avb);
        mfma_gemm<0, 1, 0><<<dim3(MROWS / 128, HH / 128), 256, 0, stream>>>(
            avb, resT + (size_t)l * HH * HH, res_b + (size_t)l * HH,
            a, nullptr, MROWS, HH, HH);
        add_ln_kernel<<<MROWS, 256, 0, stream>>>(h, hb, a,
            ln1_g + (size_t)l * HH, ln1_b + (size_t)l * HH);
        mfma_gemm<1, 0, 1><<<dim3(MROWS / 128, 4 * HH / 128), 256, 0, stream>>>(
            hb, ff1T + (size_t)l * HH * 4 * HH, ff1_b + (size_t)l * 4 * HH,
            nullptr, midb, MROWS, 4 * HH, HH);
        mfma_gemm<0, 1, 0><<<dim3(MROWS / 128, HH / 128), 256, 0, stream>>>(
            midb, ff2T + (size_t)l * 4 * HH * HH, ff2_b + (size_t)l * HH,
            a, nullptr, MROWS, HH, 4 * HH);
        add_ln_kernel<<<MROWS, 256, 0, stream>>>(h, hb, a,
            ln2_g + (size_t)l * HH, ln2_b + (size_t)l * HH);
    }

    mfma_gemm<0, 1, 0><<<dim3(MROWS / 128, VV / 128), 256, 0, stream>>>(
        hb, predT, nullptr, out_score, nullptr, MROWS, VV, HH);
    softmax_v_kernel<<<MROWS, 256, 0, stream>>>(out_score, out_prob);
}

// Round 6
// 1140.347 us; speedup vs baseline: 17.7092x; 1.0792x over previous
//
#include <hip/hip_runtime.h>
#include <math.h>

#define BB 2
#define SS 1024
#define HH 768
#define NHEAD 12
#define HDIM 64
#define NLAYER 4
#define VV 32000
#define MROWS (BB*SS)

typedef unsigned short u16;
typedef __attribute__((ext_vector_type(8))) short short8;
typedef __attribute__((ext_vector_type(4))) float f32x4;
typedef __attribute__((ext_vector_type(4))) unsigned short u16x4;

__device__ __forceinline__ u16 f2bf(float f) {
    union { float f; unsigned u; } x; x.f = f;
    unsigned r = (x.u + 0x7fff + ((x.u >> 16) & 1)) >> 16;
    return (u16)r;
}
__device__ __forceinline__ float bf2f(u16 b) {
    union { unsigned u; float f; } x; x.u = ((unsigned)b) << 16;
    return x.f;
}

__device__ __forceinline__ void gload_lds16(const u16* g, u16* l) {
    __builtin_amdgcn_global_load_lds((const __attribute__((address_space(1))) void*)g,
                                     (__attribute__((address_space(3))) void*)l, 16, 0, 0);
}

// ---------------- weight convert + transpose: W[K][N] f32 -> Wt[N][K] bf16 ----
// Coalesced float4 loads, LDS transpose, coalesced u16x4 stores.
__global__ __launch_bounds__(256) void conv_transpose(
    const float* __restrict__ W, u16* __restrict__ Wt, int K, int N) {
    int l = blockIdx.z;
    W  += (size_t)l * K * N;
    Wt += (size_t)l * K * N;
    __shared__ u16 tile[32][33];        // tile[n][k]
    int k0 = blockIdx.y * 32, n0 = blockIdx.x * 32;
    int t = threadIdx.x;                // 256
    int ky = t >> 3, nx = (t & 7) * 4;  // load: row k0+ky, cols n0+nx..+3
    float4 v = *(const float4*)(W + (size_t)(k0 + ky) * N + n0 + nx);
    tile[nx + 0][ky] = f2bf(v.x);
    tile[nx + 1][ky] = f2bf(v.y);
    tile[nx + 2][ky] = f2bf(v.z);
    tile[nx + 3][ky] = f2bf(v.w);
    __syncthreads();
    int nr = t >> 3, kc = (t & 7) * 4;  // store: row n0+nr, cols k0+kc..+3
    u16x4 o;
    o[0] = tile[nr][kc + 0]; o[1] = tile[nr][kc + 1];
    o[2] = tile[nr][kc + 2]; o[3] = tile[nr][kc + 3];
    *(u16x4*)(Wt + (size_t)(n0 + nr) * K + k0 + kc) = o;
}

// ---------------- embedding: h f32 + hb bf16 ----------------
__global__ void embed_kernel(const int* __restrict__ ids,
                             const float* __restrict__ bpe,
                             const float* __restrict__ pos,
                             float* __restrict__ h, u16* __restrict__ hb) {
    int row = blockIdx.x;
    int s = row % SS;
    int id = ids[row];
    const float4* br = (const float4*)(bpe + (size_t)id * HH);
    const float4* pr = (const float4*)(pos + (size_t)s * HH);
    float4* hr = (float4*)(h + (size_t)row * HH);
    u16x4* hbr = (u16x4*)(hb + (size_t)row * HH);
    int t = threadIdx.x;                  // 192 threads, 1 float4 each
    float4 a = br[t], c = pr[t];
    a.x += c.x; a.y += c.y; a.z += c.z; a.w += c.w;
    hr[t] = a;
    u16x4 u; u[0] = f2bf(a.x); u[1] = f2bf(a.y); u[2] = f2bf(a.z); u[3] = f2bf(a.w);
    hbr[t] = u;
}

// ---------------- MFMA GEMM: C[M][N] = A[M][K](bf16) * Wt[N][K](bf16)^T ------
// Templated M-tile (BM=128: 4 waves x 64x64; BM=64: 4 waves x 32x64).
// Grid x = M-tile (fast), y = N-tile; bijective XCD swizzle (nwg%8==0 always).
template<int BM, int ACT, int WF32, int WBF>
__global__ __launch_bounds__(256) void mfma_gemm(
    const u16* __restrict__ A, const u16* __restrict__ Wt,
    const float* __restrict__ bias, float* __restrict__ C,
    u16* __restrict__ Cb, int M, int N, int K) {
    constexpr int MR = BM / 32;         // M fragments per wave
    __shared__ u16 As[BM * 32];
    __shared__ u16 Bs[128 * 32];
    const int tid = threadIdx.x;
    const int lane = tid & 63;
    const int wid = tid >> 6;

    // XCD-aware bijective swizzle of flat block id
    const int nwg = gridDim.x * gridDim.y;
    int id = blockIdx.x + gridDim.x * blockIdx.y;
    int id2 = (nwg & 7) ? id : ((id & 7) * (nwg >> 3) + (id >> 3));
    const int brow = (id2 % gridDim.x) * BM;
    const int bcol = (id2 / gridDim.x) * 128;

    const int wr = (wid >> 1) * (BM / 2);
    const int wc = (wid & 1) * 64;
    f32x4 acc[MR][4] = {};

    const u16* Abase = A + (size_t)brow * K;
    const u16* Bbase = Wt + (size_t)bcol * K;
    const int lrow = lane & 15;
    const int lk = (lane >> 4) * 8;

    for (int kt = 0; kt < K; kt += 32) {
        __syncthreads();
#pragma unroll
        for (int c0 = 0; c0 < BM * 4; c0 += 256) {   // A: BM*4 16B chunks
            int c = c0 + tid;
            int r = c >> 2, off = (c & 3) * 8;
            gload_lds16(Abase + (size_t)r * K + kt + off, As + c * 8);
        }
#pragma unroll
        for (int c0 = 0; c0 < 512; c0 += 256) {      // B: 512 16B chunks
            int c = c0 + tid;
            int r = c >> 2, off = (c & 3) * 8;
            gload_lds16(Bbase + (size_t)r * K + kt + off, Bs + c * 8);
        }
        __syncthreads();
        short8 a[MR], b[4];
#pragma unroll
        for (int m = 0; m < MR; ++m)
            a[m] = *(const short8*)(As + (wr + m * 16 + lrow) * 32 + lk);
#pragma unroll
        for (int n = 0; n < 4; ++n)
            b[n] = *(const short8*)(Bs + (wc + n * 16 + lrow) * 32 + lk);
#pragma unroll
        for (int m = 0; m < MR; ++m)
#pragma unroll
            for (int n = 0; n < 4; ++n)
                acc[m][n] = __builtin_amdgcn_mfma_f32_16x16x32_bf16(a[m], b[n], acc[m][n], 0, 0, 0);
    }

    const int lr4 = (lane >> 4) * 4;
#pragma unroll
    for (int n = 0; n < 4; ++n) {
        int col = bcol + wc + n * 16 + lrow;
        float bv = bias ? bias[col] : 0.f;
#pragma unroll
        for (int m = 0; m < MR; ++m) {
#pragma unroll
            for (int j = 0; j < 4; ++j) {
                int row = brow + wr + m * 16 + lr4 + j;
                float v = acc[m][n][j] + bv;
                if (ACT == 1) v = 0.5f * v * (1.f + erff(v * 0.70710678118654752f));
                if (WF32) C[(size_t)row * N + col] = v;
                if (WBF)  Cb[(size_t)row * N + col] = f2bf(v);
            }
        }
    }
}

// ---------------- MFMA flash attention (bf16 QKV input) ----------------
// block = 64 q-rows of one (b,head); 4 waves; wave w owns q-rows [16w,16w+16).
// K tile [k][d] and V^T tile [d][k] bf16 in LDS, XOR-swizzled (byte^=(row&7)<<4).
__global__ __launch_bounds__(256) void attn_kernel(
    const u16* __restrict__ qkvb, const float* __restrict__ seq_mask,
    u16* __restrict__ av) {
    __shared__ u16 Ks[64 * 64];
    __shared__ u16 Vt[64 * 64];
    __shared__ u16 Ps[64 * 64];
    const int qb = blockIdx.x, hd = blockIdx.y, b = blockIdx.z;
    const int t = threadIdx.x;
    const int lane = t & 63;
    const int w = t >> 6;
    const int lrow = lane & 15;
    const int lhi = lane >> 4;
    const int q0 = qb * 64;
    const size_t rs = 3 * HH;

    // Q A-frags straight from bf16 global: row = q0+16w+lrow, k = c*32+lhi*8..+8
    short8 aq[2];
    {
        const u16* qrow = qkvb + (size_t)(b * SS + q0 + w * 16 + lrow) * rs + hd * HDIM;
        aq[0] = *(const short8*)(qrow + lhi * 8);
        aq[1] = *(const short8*)(qrow + 32 + lhi * 8);
    }

    f32x4 o[4] = {};
    float m_[4] = {-INFINITY, -INFINITY, -INFINITY, -INFINITY};
    float l_[4] = {0.f, 0.f, 0.f, 0.f};

    for (int kt = 0; kt <= qb; ++kt) {
        const int k0 = kt * 64;
        __syncthreads();                       // prior tile's LDS reads done
        // ---- stage K[k][d] and V^T[d][k] (pure u16 copies, swizzled) ----
        {
            const int kr = t >> 2, dc = t & 3;
            const u16* kbase = qkvb + (size_t)(b * SS + k0 + kr) * rs + HH + hd * HDIM + dc * 16;
            short8 kA = *(const short8*)(kbase);
            short8 kB = *(const short8*)(kbase + 8);
            char* krowp = (char*)Ks + kr * 128;
            *(short8*)(krowp + (((dc * 32 + 0)  ^ ((kr & 7) << 4)))) = kA;
            *(short8*)(krowp + (((dc * 32 + 16) ^ ((kr & 7) << 4)))) = kB;

            const u16* vbase = kbase + HH;     // V part
            short8 vA = *(const short8*)(vbase);
            short8 vB = *(const short8*)(vbase + 8);
#pragma unroll
            for (int e = 0; e < 8; ++e) {
                int d0 = dc * 16 + e;
                int d1 = dc * 16 + 8 + e;
                *(u16*)((char*)Vt + d0 * 128 + ((kr * 2) ^ ((d0 & 7) << 4))) = (u16)vA[e];
                *(u16*)((char*)Vt + d1 * 128 + ((kr * 2) ^ ((d1 & 7) << 4))) = (u16)vB[e];
            }
        }
        __syncthreads();

        // ---- S = Q K^T ----
        f32x4 s[4] = {};
        __builtin_amdgcn_s_setprio(1);
#pragma unroll
        for (int n = 0; n < 4; ++n) {
            const int krow = n * 16 + lrow;    // B-frag row = k col index
            char* kp = (char*)Ks + krow * 128;
#pragma unroll
            for (int c = 0; c < 2; ++c) {
                short8 bk = *(const short8*)(kp + ((c * 64 + lhi * 16) ^ ((krow & 7) << 4)));
                s[n] = __builtin_amdgcn_mfma_f32_16x16x32_bf16(aq[c], bk, s[n], 0, 0, 0);
            }
        }
        __builtin_amdgcn_s_setprio(0);

        // ---- online softmax (rows lhi*4+j owned by 16-lane group) ----
        float sm[4];
#pragma unroll
        for (int n = 0; n < 4; ++n) sm[n] = seq_mask[b * SS + k0 + n * 16 + lrow];
        const int diag = (kt == qb);
#pragma unroll
        for (int j = 0; j < 4; ++j) {
            const int qglob = q0 + w * 16 + lhi * 4 + j;
            float sv[4];
#pragma unroll
            for (int n = 0; n < 4; ++n) {
                const int kglob = k0 + n * 16 + lrow;
                float msk = (diag && kglob > qglob) ? 0.f : sm[n];
                sv[n] = s[n][j] * 0.125f + (1.f - msk) * (-1e9f);
            }
            float tm = fmaxf(fmaxf(sv[0], sv[1]), fmaxf(sv[2], sv[3]));
            tm = fmaxf(tm, __shfl_xor(tm, 1));
            tm = fmaxf(tm, __shfl_xor(tm, 2));
            tm = fmaxf(tm, __shfl_xor(tm, 4));
            tm = fmaxf(tm, __shfl_xor(tm, 8));
            float mn = fmaxf(m_[j], tm);
            float sc = __expf(m_[j] - mn);     // first tile: exp(-inf)=0
            float ps = 0.f;
#pragma unroll
            for (int n = 0; n < 4; ++n) {
                float p = __expf(sv[n] - mn);
                s[n][j] = p;
                ps += p;
            }
            ps += __shfl_xor(ps, 1);
            ps += __shfl_xor(ps, 2);
            ps += __shfl_xor(ps, 4);
            ps += __shfl_xor(ps, 8);
            l_[j] = l_[j] * sc + ps;
            m_[j] = mn;
#pragma unroll
            for (int dn = 0; dn < 4; ++dn) o[dn][j] *= sc;
        }

        // ---- P -> LDS (bf16, swizzled); wave-local strip ----
#pragma unroll
        for (int j = 0; j < 4; ++j) {
            const int prow = w * 16 + lhi * 4 + j;
            char* pp = (char*)Ps + prow * 128;
#pragma unroll
            for (int n = 0; n < 4; ++n)
                *(u16*)(pp + ((n * 32 + lrow * 2) ^ ((prow & 7) << 4))) = f2bf(s[n][j]);
        }

        // ---- PV: O += P * V^T ----
        const int arow = w * 16 + lrow;
        char* ap_p = (char*)Ps + arow * 128;
        __builtin_amdgcn_s_setprio(1);
#pragma unroll
        for (int c = 0; c < 2; ++c) {
            short8 ap = *(const short8*)(ap_p + ((c * 64 + lhi * 16) ^ ((arow & 7) << 4)));
#pragma unroll
            for (int dn = 0; dn < 4; ++dn) {
                const int vrow = dn * 16 + lrow;
                short8 bv = *(const short8*)((char*)Vt + vrow * 128 +
                                             ((c * 64 + lhi * 16) ^ ((vrow & 7) << 4)));
                o[dn] = __builtin_amdgcn_mfma_f32_16x16x32_bf16(ap, bv, o[dn], 0, 0, 0);
            }
        }
        __builtin_amdgcn_s_setprio(0);
    }

    // ---- epilogue: normalize + store bf16 ----
#pragma unroll
    for (int j = 0; j < 4; ++j) {
        const int q = q0 + w * 16 + lhi * 4 + j;
        const float inv = 1.f / l_[j];
        u16* orow = av + (size_t)(b * SS + q) * HH + hd * HDIM;
#pragma unroll
        for (int dn = 0; dn < 4; ++dn)
            orow[dn * 16 + lrow] = f2bf(o[dn][j] * inv);
    }
}

// ---------------- residual add + layernorm: h f32 + hb bf16 ----------------
__global__ void add_ln_kernel(float* __restrict__ h, u16* __restrict__ hb,
                              const float* __restrict__ a,
                              const float* __restrict__ g,
                              const float* __restrict__ bta) {
    int row = blockIdx.x;
    int t = threadIdx.x;
    __shared__ float red[256];
    size_t base = (size_t)row * HH;
    float x0 = h[base + t]       + a[base + t];
    float x1 = h[base + t + 256] + a[base + t + 256];
    float x2 = h[base + t + 512] + a[base + t + 512];

    red[t] = x0 + x1 + x2;
    __syncthreads();
    for (int o = 128; o; o >>= 1) { if (t < o) red[t] += red[t + o]; __syncthreads(); }
    float mean = red[0] * (1.0f / 768.0f);
    __syncthreads();

    float d0 = x0 - mean, d1 = x1 - mean, d2 = x2 - mean;
    red[t] = d0 * d0 + d1 * d1 + d2 * d2;
    __syncthreads();
    for (int o = 128; o; o >>= 1) { if (t < o) red[t] += red[t + o]; __syncthreads(); }
    float var = red[0] * (1.0f / 768.0f);
    float inv = 1.0f / sqrtf(var + 1e-5f);

    float y0 = g[t]       * d0 * inv + bta[t];
    float y1 = g[t + 256] * d1 * inv + bta[t + 256];
    float y2 = g[t + 512] * d2 * inv + bta[t + 512];
    h[base + t] = y0;       hb[base + t] = f2bf(y0);
    h[base + t + 256] = y1; hb[base + t + 256] = f2bf(y1);
    h[base + t + 512] = y2; hb[base + t + 512] = f2bf(y2);
}

// ---------------- single-pass row softmax over V=32000 ----------------
// Score row staged bf16 in LDS (62.5KB): 1 HBM read + 1 HBM write.
__global__ __launch_bounds__(256) void softmax_v_kernel(
    const float* __restrict__ score, float* __restrict__ prob) {
    __shared__ u16 srow[VV];        // 64000 B
    __shared__ float red[256];
    int row = blockIdx.x;
    int t = threadIdx.x;
    const float4* sr = (const float4*)(score + (size_t)row * VV);
    float4* pr = (float4*)(prob + (size_t)row * VV);
    const int n4 = VV / 4;          // 8000

    float mx = -INFINITY;
    for (int i = t; i < n4; i += 256) {
        float4 v = sr[i];
        u16x4 u; u[0] = f2bf(v.x); u[1] = f2bf(v.y); u[2] = f2bf(v.z); u[3] = f2bf(v.w);
        *(u16x4*)(srow + i * 4) = u;
        mx = fmaxf(mx, fmaxf(fmaxf(bf2f(u[0]), bf2f(u[1])), fmaxf(bf2f(u[2]), bf2f(u[3]))));
    }
    red[t] = mx; __syncthreads();
    for (int o = 128; o; o >>= 1) { if (t < o) red[t] = fmaxf(red[t], red[t + o]); __syncthreads(); }
    mx = red[0];
    __syncthreads();

    float s = 0.f;
    for (int i = t; i < n4; i += 256) {
        u16x4 u = *(const u16x4*)(srow + i * 4);
        s += __expf(bf2f(u[0]) - mx) + __expf(bf2f(u[1]) - mx)
           + __expf(bf2f(u[2]) - mx) + __expf(bf2f(u[3]) - mx);
    }
    red[t] = s; __syncthreads();
    for (int o = 128; o; o >>= 1) { if (t < o) red[t] += red[t + o]; __syncthreads(); }
    float inv = 1.0f / red[0];

    for (int i = t; i < n4; i += 256) {
        u16x4 u = *(const u16x4*)(srow + i * 4);
        float4 o4;
        o4.x = __expf(bf2f(u[0]) - mx) * inv; o4.y = __expf(bf2f(u[1]) - mx) * inv;
        o4.z = __expf(bf2f(u[2]) - mx) * inv; o4.w = __expf(bf2f(u[3]) - mx) * inv;
        pr[i] = o4;
    }
}

extern "C" void kernel_launch(void* const* d_in, const int* in_sizes, int n_in,
                              void* d_out, int out_size, void* d_ws, size_t ws_size,
                              hipStream_t stream) {
    const int*   ids      = (const int*)d_in[0];
    const float* seq_mask = (const float*)d_in[1];
    const float* bpe      = (const float*)d_in[2];
    const float* pos      = (const float*)d_in[3];
    const float* qkv_w    = (const float*)d_in[4];
    const float* qkv_b    = (const float*)d_in[5];
    const float* res_w    = (const float*)d_in[6];
    const float* res_b    = (const float*)d_in[7];
    const float* ln1_g    = (const float*)d_in[8];
    const float* ln1_b    = (const float*)d_in[9];
    const float* ff1_w    = (const float*)d_in[10];
    const float* ff1_b    = (const float*)d_in[11];
    const float* ff2_w    = (const float*)d_in[12];
    const float* ff2_b    = (const float*)d_in[13];
    const float* ln2_g    = (const float*)d_in[14];
    const float* ln2_b    = (const float*)d_in[15];
    const float* pred_w   = (const float*)d_in[16];

    float* out_score = (float*)d_out;
    float* out_prob  = out_score + (size_t)MROWS * VV;

    // arena layout
    size_t off = 0;
    auto take = [&](size_t bytes) -> size_t {
        size_t p = off; off += (bytes + 255) & ~(size_t)255; return p;
    };
    const size_t o_qkvT = take((size_t)NLAYER * HH * 3 * HH * 2);
    const size_t o_resT = take((size_t)NLAYER * HH * HH * 2);
    const size_t o_ff1T = take((size_t)NLAYER * HH * 4 * HH * 2);
    const size_t o_ff2T = take((size_t)NLAYER * 4 * HH * HH * 2);
    const size_t o_predT = take((size_t)HH * VV * 2);
    const size_t o_h    = take((size_t)MROWS * HH * 4);
    const size_t o_a    = take((size_t)MROWS * HH * 4);
    const size_t o_qkvb = take((size_t)MROWS * 3 * HH * 2);
    const size_t o_hb   = take((size_t)MROWS * HH * 2);
    const size_t o_avb  = take((size_t)MROWS * HH * 2);
    const size_t o_midb = take((size_t)MROWS * 4 * HH * 2);
    const size_t need = off;

    char* arena = (ws_size >= need) ? (char*)d_ws : (char*)out_prob;
    u16*   qkvT = (u16*)(arena + o_qkvT);
    u16*   resT = (u16*)(arena + o_resT);
    u16*   ff1T = (u16*)(arena + o_ff1T);
    u16*   ff2T = (u16*)(arena + o_ff2T);
    u16*   predT = (u16*)(arena + o_predT);
    float* h    = (float*)(arena + o_h);
    float* a    = (float*)(arena + o_a);
    u16*   qkvb = (u16*)(arena + o_qkvb);
    u16*   hb   = (u16*)(arena + o_hb);
    u16*   avb  = (u16*)(arena + o_avb);
    u16*   midb = (u16*)(arena + o_midb);

    conv_transpose<<<dim3(3 * HH / 32, HH / 32, NLAYER), 256, 0, stream>>>(qkv_w, qkvT, HH, 3 * HH);
    conv_transpose<<<dim3(HH / 32, HH / 32, NLAYER), 256, 0, stream>>>(res_w, resT, HH, HH);
    conv_transpose<<<dim3(4 * HH / 32, HH / 32, NLAYER), 256, 0, stream>>>(ff1_w, ff1T, HH, 4 * HH);
    conv_transpose<<<dim3(HH / 32, 4 * HH / 32, NLAYER), 256, 0, stream>>>(ff2_w, ff2T, 4 * HH, HH);
    conv_transpose<<<dim3(VV / 32, HH / 32, 1), 256, 0, stream>>>(pred_w, predT, HH, VV);

    embed_kernel<<<MROWS, 192, 0, stream>>>(ids, bpe, pos, h, hb);

    for (int l = 0; l < NLAYER; ++l) {
        mfma_gemm<128, 0, 0, 1><<<dim3(MROWS / 128, 3 * HH / 128), 256, 0, stream>>>(
            hb, qkvT + (size_t)l * HH * 3 * HH, qkv_b + (size_t)l * 3 * HH,
            nullptr, qkvb, MROWS, 3 * HH, HH);
        attn_kernel<<<dim3(SS / 64, NHEAD, BB), 256, 0, stream>>>(qkvb, seq_mask, avb);
        mfma_gemm<64, 0, 1, 0><<<dim3(MROWS / 64, HH / 128), 256, 0, stream>>>(
            avb, resT + (size_t)l * HH * HH, res_b + (size_t)l * HH,
            a, nullptr, MROWS, HH, HH);
        add_ln_kernel<<<MROWS, 256, 0, stream>>>(h, hb, a,
            ln1_g + (size_t)l * HH, ln1_b + (size_t)l * HH);
        mfma_gemm<128, 1, 0, 1><<<dim3(MROWS / 128, 4 * HH / 128), 256, 0, stream>>>(
            hb, ff1T + (size_t)l * HH * 4 * HH, ff1_b + (size_t)l * 4 * HH,
            nullptr, midb, MROWS, 4 * HH, HH);
        mfma_gemm<64, 0, 1, 0><<<dim3(MROWS / 64, HH / 128), 256, 0, stream>>>(
            midb, ff2T + (size_t)l * 4 * HH * HH, ff2_b + (size_t)l * HH,
            a, nullptr, MROWS, HH, 4 * HH);
        add_ln_kernel<<<MROWS, 256, 0, stream>>>(h, hb, a,
            ln2_g + (size_t)l * HH, ln2_b + (size_t)l * HH);
    }

    mfma_gemm<128, 0, 1, 0><<<dim3(MROWS / 128, VV / 128), 256, 0, stream>>>(
        hb, predT, nullptr, out_score, nullptr, MROWS, VV, HH);
    softmax_v_kernel<<<MROWS, 256, 0, stream>>>(out_score, out_prob);
}

// Round 7
// 1106.458 us; speedup vs baseline: 18.2517x; 1.0306x over previous
//
#include <hip/hip_runtime.h>
#include <math.h>

#define BB 2
#define SS 1024
#define HH 768
#define NHEAD 12
#define HDIM 64
#define NLAYER 4
#define VV 32000
#define MROWS (BB*SS)

typedef unsigned short u16;
typedef __attribute__((ext_vector_type(8))) short short8;
typedef __attribute__((ext_vector_type(4))) float f32x4;
typedef __attribute__((ext_vector_type(4))) unsigned short u16x4;

__device__ __forceinline__ u16 f2bf(float f) {
    union { float f; unsigned u; } x; x.f = f;
    unsigned r = (x.u + 0x7fff + ((x.u >> 16) & 1)) >> 16;
    return (u16)r;
}
__device__ __forceinline__ float bf2f(u16 b) {
    union { unsigned u; float f; } x; x.u = ((unsigned)b) << 16;
    return x.f;
}

__device__ __forceinline__ void gload_lds16(const u16* g, u16* l) {
    __builtin_amdgcn_global_load_lds((const __attribute__((address_space(1))) void*)g,
                                     (__attribute__((address_space(3))) void*)l, 16, 0, 0);
}

// ---------------- weight convert + transpose: W[K][N] f32 -> Wt[N][K] bf16 ----
// Coalesced float4 loads, LDS transpose, coalesced u16x4 stores.
__global__ __launch_bounds__(256) void conv_transpose(
    const float* __restrict__ W, u16* __restrict__ Wt, int K, int N) {
    int l = blockIdx.z;
    W  += (size_t)l * K * N;
    Wt += (size_t)l * K * N;
    __shared__ u16 tile[32][33];        // tile[n][k]
    int k0 = blockIdx.y * 32, n0 = blockIdx.x * 32;
    int t = threadIdx.x;                // 256
    int ky = t >> 3, nx = (t & 7) * 4;  // load: row k0+ky, cols n0+nx..+3
    float4 v = *(const float4*)(W + (size_t)(k0 + ky) * N + n0 + nx);
    tile[nx + 0][ky] = f2bf(v.x);
    tile[nx + 1][ky] = f2bf(v.y);
    tile[nx + 2][ky] = f2bf(v.z);
    tile[nx + 3][ky] = f2bf(v.w);
    __syncthreads();
    int nr = t >> 3, kc = (t & 7) * 4;  // store: row n0+nr, cols k0+kc..+3
    u16x4 o;
    o[0] = tile[nr][kc + 0]; o[1] = tile[nr][kc + 1];
    o[2] = tile[nr][kc + 2]; o[3] = tile[nr][kc + 3];
    *(u16x4*)(Wt + (size_t)(n0 + nr) * K + k0 + kc) = o;
}

// ---------------- embedding: h f32 + hb bf16 ----------------
__global__ void embed_kernel(const int* __restrict__ ids,
                             const float* __restrict__ bpe,
                             const float* __restrict__ pos,
                             float* __restrict__ h, u16* __restrict__ hb) {
    int row = blockIdx.x;
    int s = row % SS;
    int id = ids[row];
    const float4* br = (const float4*)(bpe + (size_t)id * HH);
    const float4* pr = (const float4*)(pos + (size_t)s * HH);
    float4* hr = (float4*)(h + (size_t)row * HH);
    u16x4* hbr = (u16x4*)(hb + (size_t)row * HH);
    int t = threadIdx.x;                  // 192 threads, 1 float4 each
    float4 a = br[t], c = pr[t];
    a.x += c.x; a.y += c.y; a.z += c.z; a.w += c.w;
    hr[t] = a;
    u16x4 u; u[0] = f2bf(a.x); u[1] = f2bf(a.y); u[2] = f2bf(a.z); u[3] = f2bf(a.w);
    hbr[t] = u;
}

// ---------------- MFMA GEMM: C[M][N] = A[M][K](bf16) * Wt[N][K](bf16)^T ------
// 2-phase double-buffered: stage tile t+1 (global_load_lds) before computing
// tile t; raw s_barrier + counted vmcnt (never 0 mid-loop, T3/T4 minimum).
template<int BM, int ACT, int WF32, int WBF>
__global__ __launch_bounds__(256) void mfma_gemm(
    const u16* __restrict__ A, const u16* __restrict__ Wt,
    const float* __restrict__ bias, float* __restrict__ C,
    u16* __restrict__ Cb, int M, int N, int K) {
    constexpr int MR = BM / 32;         // M fragments per wave
    __shared__ u16 As[2 * BM * 32];
    __shared__ u16 Bs[2 * 128 * 32];
    const int tid = threadIdx.x;
    const int lane = tid & 63;
    const int wid = tid >> 6;

    // XCD-aware bijective swizzle of flat block id
    const int nwg = gridDim.x * gridDim.y;
    int id = blockIdx.x + gridDim.x * blockIdx.y;
    int id2 = (nwg & 7) ? id : ((id & 7) * (nwg >> 3) + (id >> 3));
    const int brow = (id2 % gridDim.x) * BM;
    const int bcol = (id2 / gridDim.x) * 128;

    const int wr = (wid >> 1) * (BM / 2);
    const int wc = (wid & 1) * 64;
    f32x4 acc[MR][4] = {};

    const u16* Abase = A + (size_t)brow * K;
    const u16* Bbase = Wt + (size_t)bcol * K;
    const int lrow = lane & 15;
    const int lk = (lane >> 4) * 8;

    auto stage = [&](u16* Ad, u16* Bd, int kt) {
#pragma unroll
        for (int c0 = 0; c0 < BM * 4; c0 += 256) {   // A: BM*4 16B chunks
            int c = c0 + tid;
            int r = c >> 2, off = (c & 3) * 8;
            gload_lds16(Abase + (size_t)r * K + kt + off, Ad + c * 8);
        }
#pragma unroll
        for (int c0 = 0; c0 < 512; c0 += 256) {      // B: 512 16B chunks
            int c = c0 + tid;
            int r = c >> 2, off = (c & 3) * 8;
            gload_lds16(Bbase + (size_t)r * K + kt + off, Bd + c * 8);
        }
    };

    const int nt = K / 32;
    stage(As, Bs, 0);
    for (int t = 0; t < nt; ++t) {
        u16* Ac = As + (t & 1) * (BM * 32);
        u16* Bc = Bs + (t & 1) * (128 * 32);
        if (t + 1 < nt) {
            stage(As + ((t + 1) & 1) * (BM * 32),
                  Bs + ((t + 1) & 1) * (128 * 32), (t + 1) * 32);
            if constexpr (BM == 128) asm volatile("s_waitcnt vmcnt(4)" ::: "memory");
            else                     asm volatile("s_waitcnt vmcnt(3)" ::: "memory");
        } else {
            asm volatile("s_waitcnt vmcnt(0)" ::: "memory");
        }
        __builtin_amdgcn_s_barrier();
        __builtin_amdgcn_sched_barrier(0);

        short8 a[MR], b[4];
#pragma unroll
        for (int m = 0; m < MR; ++m)
            a[m] = *(const short8*)(Ac + (wr + m * 16 + lrow) * 32 + lk);
#pragma unroll
        for (int n = 0; n < 4; ++n)
            b[n] = *(const short8*)(Bc + (wc + n * 16 + lrow) * 32 + lk);
#pragma unroll
        for (int m = 0; m < MR; ++m)
#pragma unroll
            for (int n = 0; n < 4; ++n)
                acc[m][n] = __builtin_amdgcn_mfma_f32_16x16x32_bf16(a[m], b[n], acc[m][n], 0, 0, 0);

        __builtin_amdgcn_sched_barrier(0);
        __builtin_amdgcn_s_barrier();
    }

    const int lr4 = (lane >> 4) * 4;
#pragma unroll
    for (int n = 0; n < 4; ++n) {
        int col = bcol + wc + n * 16 + lrow;
        float bv = bias ? bias[col] : 0.f;
#pragma unroll
        for (int m = 0; m < MR; ++m) {
#pragma unroll
            for (int j = 0; j < 4; ++j) {
                int row = brow + wr + m * 16 + lr4 + j;
                float v = acc[m][n][j] + bv;
                if (ACT == 1) v = 0.5f * v * (1.f + erff(v * 0.70710678118654752f));
                if (WF32) C[(size_t)row * N + col] = v;
                if (WBF)  Cb[(size_t)row * N + col] = f2bf(v);
            }
        }
    }
}

// ---------------- MFMA flash attention (bf16 QKV input) ----------------
// block = 64 q-rows of one (b,head); 4 waves; wave w owns q-rows [16w,16w+16).
// K tile [k][d] and V^T tile [d][k] bf16 in LDS, XOR-swizzled (byte^=(row&7)<<4).
// Reg-prefetch of next K/V tile overlaps global latency with compute (T14);
// heavy blocks (large qb) dispatched first.
__global__ __launch_bounds__(256) void attn_kernel(
    const u16* __restrict__ qkvb, const float* __restrict__ seq_mask,
    u16* __restrict__ av) {
    __shared__ u16 Ks[64 * 64];
    __shared__ u16 Vt[64 * 64];
    __shared__ u16 Ps[64 * 64];
    const int qb = gridDim.x - 1 - blockIdx.x;   // heavy-first
    const int hd = blockIdx.y, b = blockIdx.z;
    const int t = threadIdx.x;
    const int lane = t & 63;
    const int w = t >> 6;
    const int lrow = lane & 15;
    const int lhi = lane >> 4;
    const int q0 = qb * 64;
    const size_t rs = 3 * HH;

    // Q A-frags straight from bf16 global: row = q0+16w+lrow, k = c*32+lhi*8..+8
    short8 aq[2];
    {
        const u16* qrow = qkvb + (size_t)(b * SS + q0 + w * 16 + lrow) * rs + hd * HDIM;
        aq[0] = *(const short8*)(qrow + lhi * 8);
        aq[1] = *(const short8*)(qrow + 32 + lhi * 8);
    }

    f32x4 o[4] = {};
    float m_[4] = {-INFINITY, -INFINITY, -INFINITY, -INFINITY};
    float l_[4] = {0.f, 0.f, 0.f, 0.f};

    const int kr = t >> 2, dc = t & 3;
    short8 kA, kB, vA, vB;
    {
        const u16* kbase = qkvb + (size_t)(b * SS + kr) * rs + HH + hd * HDIM + dc * 16;
        kA = *(const short8*)(kbase);
        kB = *(const short8*)(kbase + 8);
        vA = *(const short8*)(kbase + HH);
        vB = *(const short8*)(kbase + HH + 8);
    }

    for (int kt = 0; kt <= qb; ++kt) {
        const int k0 = kt * 64;
        __syncthreads();                       // prior tile's LDS reads done
        // ---- write prefetched K/V regs to LDS (swizzled) ----
        {
            char* krowp = (char*)Ks + kr * 128;
            *(short8*)(krowp + (((dc * 32 + 0)  ^ ((kr & 7) << 4)))) = kA;
            *(short8*)(krowp + (((dc * 32 + 16) ^ ((kr & 7) << 4)))) = kB;
#pragma unroll
            for (int e = 0; e < 8; ++e) {
                int d0 = dc * 16 + e;
                int d1 = dc * 16 + 8 + e;
                *(u16*)((char*)Vt + d0 * 128 + ((kr * 2) ^ ((d0 & 7) << 4))) = (u16)vA[e];
                *(u16*)((char*)Vt + d1 * 128 + ((kr * 2) ^ ((d1 & 7) << 4))) = (u16)vB[e];
            }
        }
        __syncthreads();

        // ---- issue next tile's loads (overlap latency with compute) ----
        if (kt < qb) {
            const u16* kbase = qkvb + (size_t)(b * SS + k0 + 64 + kr) * rs + HH + hd * HDIM + dc * 16;
            kA = *(const short8*)(kbase);
            kB = *(const short8*)(kbase + 8);
            vA = *(const short8*)(kbase + HH);
            vB = *(const short8*)(kbase + HH + 8);
        }

        // ---- S = Q K^T ----
        f32x4 s[4] = {};
        __builtin_amdgcn_s_setprio(1);
#pragma unroll
        for (int n = 0; n < 4; ++n) {
            const int krow = n * 16 + lrow;    // B-frag row = k col index
            char* kp = (char*)Ks + krow * 128;
#pragma unroll
            for (int c = 0; c < 2; ++c) {
                short8 bk = *(const short8*)(kp + ((c * 64 + lhi * 16) ^ ((krow & 7) << 4)));
                s[n] = __builtin_amdgcn_mfma_f32_16x16x32_bf16(aq[c], bk, s[n], 0, 0, 0);
            }
        }
        __builtin_amdgcn_s_setprio(0);

        // ---- online softmax (rows lhi*4+j owned by 16-lane group) ----
        float sm[4];
#pragma unroll
        for (int n = 0; n < 4; ++n) sm[n] = seq_mask[b * SS + k0 + n * 16 + lrow];
        const int diag = (kt == qb);
#pragma unroll
        for (int j = 0; j < 4; ++j) {
            const int qglob = q0 + w * 16 + lhi * 4 + j;
            float sv[4];
#pragma unroll
            for (int n = 0; n < 4; ++n) {
                const int kglob = k0 + n * 16 + lrow;
                float msk = (diag && kglob > qglob) ? 0.f : sm[n];
                sv[n] = s[n][j] * 0.125f + (1.f - msk) * (-1e9f);
            }
            float tm = fmaxf(fmaxf(sv[0], sv[1]), fmaxf(sv[2], sv[3]));
            tm = fmaxf(tm, __shfl_xor(tm, 1));
            tm = fmaxf(tm, __shfl_xor(tm, 2));
            tm = fmaxf(tm, __shfl_xor(tm, 4));
            tm = fmaxf(tm, __shfl_xor(tm, 8));
            float mn = fmaxf(m_[j], tm);
            float sc = __expf(m_[j] - mn);     // first tile: exp(-inf)=0
            float ps = 0.f;
#pragma unroll
            for (int n = 0; n < 4; ++n) {
                float p = __expf(sv[n] - mn);
                s[n][j] = p;
                ps += p;
            }
            ps += __shfl_xor(ps, 1);
            ps += __shfl_xor(ps, 2);
            ps += __shfl_xor(ps, 4);
            ps += __shfl_xor(ps, 8);
            l_[j] = l_[j] * sc + ps;
            m_[j] = mn;
#pragma unroll
            for (int dn = 0; dn < 4; ++dn) o[dn][j] *= sc;
        }

        // ---- P -> LDS (bf16, swizzled); wave-local strip ----
#pragma unroll
        for (int j = 0; j < 4; ++j) {
            const int prow = w * 16 + lhi * 4 + j;
            char* pp = (char*)Ps + prow * 128;
#pragma unroll
            for (int n = 0; n < 4; ++n)
                *(u16*)(pp + ((n * 32 + lrow * 2) ^ ((prow & 7) << 4))) = f2bf(s[n][j]);
        }

        // ---- PV: O += P * V^T ----
        const int arow = w * 16 + lrow;
        char* ap_p = (char*)Ps + arow * 128;
        __builtin_amdgcn_s_setprio(1);
#pragma unroll
        for (int c = 0; c < 2; ++c) {
            short8 ap = *(const short8*)(ap_p + ((c * 64 + lhi * 16) ^ ((arow & 7) << 4)));
#pragma unroll
            for (int dn = 0; dn < 4; ++dn) {
                const int vrow = dn * 16 + lrow;
                short8 bv = *(const short8*)((char*)Vt + vrow * 128 +
                                             ((c * 64 + lhi * 16) ^ ((vrow & 7) << 4)));
                o[dn] = __builtin_amdgcn_mfma_f32_16x16x32_bf16(ap, bv, o[dn], 0, 0, 0);
            }
        }
        __builtin_amdgcn_s_setprio(0);
    }

    // ---- epilogue: normalize + store bf16 ----
#pragma unroll
    for (int j = 0; j < 4; ++j) {
        const int q = q0 + w * 16 + lhi * 4 + j;
        const float inv = 1.f / l_[j];
        u16* orow = av + (size_t)(b * SS + q) * HH + hd * HDIM;
#pragma unroll
        for (int dn = 0; dn < 4; ++dn)
            orow[dn * 16 + lrow] = f2bf(o[dn][j] * inv);
    }
}

// ---------------- residual add + layernorm: h f32 + hb bf16 ----------------
__global__ void add_ln_kernel(float* __restrict__ h, u16* __restrict__ hb,
                              const float* __restrict__ a,
                              const float* __restrict__ g,
                              const float* __restrict__ bta) {
    int row = blockIdx.x;
    int t = threadIdx.x;
    __shared__ float red[256];
    size_t base = (size_t)row * HH;
    float x0 = h[base + t]       + a[base + t];
    float x1 = h[base + t + 256] + a[base + t + 256];
    float x2 = h[base + t + 512] + a[base + t + 512];

    red[t] = x0 + x1 + x2;
    __syncthreads();
    for (int o = 128; o; o >>= 1) { if (t < o) red[t] += red[t + o]; __syncthreads(); }
    float mean = red[0] * (1.0f / 768.0f);
    __syncthreads();

    float d0 = x0 - mean, d1 = x1 - mean, d2 = x2 - mean;
    red[t] = d0 * d0 + d1 * d1 + d2 * d2;
    __syncthreads();
    for (int o = 128; o; o >>= 1) { if (t < o) red[t] += red[t + o]; __syncthreads(); }
    float var = red[0] * (1.0f / 768.0f);
    float inv = 1.0f / sqrtf(var + 1e-5f);

    float y0 = g[t]       * d0 * inv + bta[t];
    float y1 = g[t + 256] * d1 * inv + bta[t + 256];
    float y2 = g[t + 512] * d2 * inv + bta[t + 512];
    h[base + t] = y0;       hb[base + t] = f2bf(y0);
    h[base + t + 256] = y1; hb[base + t + 256] = f2bf(y1);
    h[base + t + 512] = y2; hb[base + t + 512] = f2bf(y2);
}

// ---------------- single-pass row softmax over V=32000 ----------------
// Score row staged bf16 in LDS (62.5KB): 1 HBM read + 1 HBM write.
// 512 threads -> 16 waves/CU at 2 blocks/CU for BW.
__global__ __launch_bounds__(512) void softmax_v_kernel(
    const float* __restrict__ score, float* __restrict__ prob) {
    __shared__ u16 srow[VV];        // 64000 B
    __shared__ float red[512];
    int row = blockIdx.x;
    int t = threadIdx.x;
    const float4* sr = (const float4*)(score + (size_t)row * VV);
    float4* pr = (float4*)(prob + (size_t)row * VV);
    const int n4 = VV / 4;          // 8000

    float mx = -INFINITY;
    for (int i = t; i < n4; i += 512) {
        float4 v = sr[i];
        u16x4 u; u[0] = f2bf(v.x); u[1] = f2bf(v.y); u[2] = f2bf(v.z); u[3] = f2bf(v.w);
        *(u16x4*)(srow + i * 4) = u;
        mx = fmaxf(mx, fmaxf(fmaxf(bf2f(u[0]), bf2f(u[1])), fmaxf(bf2f(u[2]), bf2f(u[3]))));
    }
    red[t] = mx; __syncthreads();
    for (int o = 256; o; o >>= 1) { if (t < o) red[t] = fmaxf(red[t], red[t + o]); __syncthreads(); }
    mx = red[0];
    __syncthreads();

    float s = 0.f;
    for (int i = t; i < n4; i += 512) {
        u16x4 u = *(const u16x4*)(srow + i * 4);
        s += __expf(bf2f(u[0]) - mx) + __expf(bf2f(u[1]) - mx)
           + __expf(bf2f(u[2]) - mx) + __expf(bf2f(u[3]) - mx);
    }
    red[t] = s; __syncthreads();
    for (int o = 256; o; o >>= 1) { if (t < o) red[t] += red[t + o]; __syncthreads(); }
    float inv = 1.0f / red[0];

    for (int i = t; i < n4; i += 512) {
        u16x4 u = *(const u16x4*)(srow + i * 4);
        float4 o4;
        o4.x = __expf(bf2f(u[0]) - mx) * inv; o4.y = __expf(bf2f(u[1]) - mx) * inv;
        o4.z = __expf(bf2f(u[2]) - mx) * inv; o4.w = __expf(bf2f(u[3]) - mx) * inv;
        pr[i] = o4;
    }
}

extern "C" void kernel_launch(void* const* d_in, const int* in_sizes, int n_in,
                              void* d_out, int out_size, void* d_ws, size_t ws_size,
                              hipStream_t stream) {
    const int*   ids      = (const int*)d_in[0];
    const float* seq_mask = (const float*)d_in[1];
    const float* bpe      = (const float*)d_in[2];
    const float* pos      = (const float*)d_in[3];
    const float* qkv_w    = (const float*)d_in[4];
    const float* qkv_b    = (const float*)d_in[5];
    const float* res_w    = (const float*)d_in[6];
    const float* res_b    = (const float*)d_in[7];
    const float* ln1_g    = (const float*)d_in[8];
    const float* ln1_b    = (const float*)d_in[9];
    const float* ff1_w    = (const float*)d_in[10];
    const float* ff1_b    = (const float*)d_in[11];
    const float* ff2_w    = (const float*)d_in[12];
    const float* ff2_b    = (const float*)d_in[13];
    const float* ln2_g    = (const float*)d_in[14];
    const float* ln2_b    = (const float*)d_in[15];
    const float* pred_w   = (const float*)d_in[16];

    float* out_score = (float*)d_out;
    float* out_prob  = out_score + (size_t)MROWS * VV;

    // arena layout
    size_t off = 0;
    auto take = [&](size_t bytes) -> size_t {
        size_t p = off; off += (bytes + 255) & ~(size_t)255; return p;
    };
    const size_t o_qkvT = take((size_t)NLAYER * HH * 3 * HH * 2);
    const size_t o_resT = take((size_t)NLAYER * HH * HH * 2);
    const size_t o_ff1T = take((size_t)NLAYER * HH * 4 * HH * 2);
    const size_t o_ff2T = take((size_t)NLAYER * 4 * HH * HH * 2);
    const size_t o_predT = take((size_t)HH * VV * 2);
    const size_t o_h    = take((size_t)MROWS * HH * 4);
    const size_t o_a    = take((size_t)MROWS * HH * 4);
    const size_t o_qkvb = take((size_t)MROWS * 3 * HH * 2);
    const size_t o_hb   = take((size_t)MROWS * HH * 2);
    const size_t o_avb  = take((size_t)MROWS * HH * 2);
    const size_t o_midb = take((size_t)MROWS * 4 * HH * 2);
    const size_t need = off;

    char* arena = (ws_size >= need) ? (char*)d_ws : (char*)out_prob;
    u16*   qkvT = (u16*)(arena + o_qkvT);
    u16*   resT = (u16*)(arena + o_resT);
    u16*   ff1T = (u16*)(arena + o_ff1T);
    u16*   ff2T = (u16*)(arena + o_ff2T);
    u16*   predT = (u16*)(arena + o_predT);
    float* h    = (float*)(arena + o_h);
    float* a    = (float*)(arena + o_a);
    u16*   qkvb = (u16*)(arena + o_qkvb);
    u16*   hb   = (u16*)(arena + o_hb);
    u16*   avb  = (u16*)(arena + o_avb);
    u16*   midb = (u16*)(arena + o_midb);

    conv_transpose<<<dim3(3 * HH / 32, HH / 32, NLAYER), 256, 0, stream>>>(qkv_w, qkvT, HH, 3 * HH);
    conv_transpose<<<dim3(HH / 32, HH / 32, NLAYER), 256, 0, stream>>>(res_w, resT, HH, HH);
    conv_transpose<<<dim3(4 * HH / 32, HH / 32, NLAYER), 256, 0, stream>>>(ff1_w, ff1T, HH, 4 * HH);
    conv_transpose<<<dim3(HH / 32, 4 * HH / 32, NLAYER), 256, 0, stream>>>(ff2_w, ff2T, 4 * HH, HH);
    conv_transpose<<<dim3(VV / 32, HH / 32, 1), 256, 0, stream>>>(pred_w, predT, HH, VV);

    embed_kernel<<<MROWS, 192, 0, stream>>>(ids, bpe, pos, h, hb);

    for (int l = 0; l < NLAYER; ++l) {
        mfma_gemm<128, 0, 0, 1><<<dim3(MROWS / 128, 3 * HH / 128), 256, 0, stream>>>(
            hb, qkvT + (size_t)l * HH * 3 * HH, qkv_b + (size_t)l * 3 * HH,
            nullptr, qkvb, MROWS, 3 * HH, HH);
        attn_kernel<<<dim3(SS / 64, NHEAD, BB), 256, 0, stream>>>(qkvb, seq_mask, avb);
        mfma_gemm<64, 0, 1, 0><<<dim3(MROWS / 64, HH / 128), 256, 0, stream>>>(
            avb, resT + (size_t)l * HH * HH, res_b + (size_t)l * HH,
            a, nullptr, MROWS, HH, HH);
        add_ln_kernel<<<MROWS, 256, 0, stream>>>(h, hb, a,
            ln1_g + (size_t)l * HH, ln1_b + (size_t)l * HH);
        mfma_gemm<128, 1, 0, 1><<<dim3(MROWS / 128, 4 * HH / 128), 256, 0, stream>>>(
            hb, ff1T + (size_t)l * HH * 4 * HH, ff1_b + (size_t)l * 4 * HH,
            nullptr, midb, MROWS, 4 * HH, HH);
        mfma_gemm<64, 0, 1, 0><<<dim3(MROWS / 64, HH / 128), 256, 0, stream>>>(
            midb, ff2T + (size_t)l * 4 * HH * HH, ff2_b + (size_t)l * HH,
            a, nullptr, MROWS, HH, 4 * HH);
        add_ln_kernel<<<MROWS, 256, 0, stream>>>(h, hb, a,
            ln2_g + (size_t)l * HH, ln2_b + (size_t)l * HH);
    }

    mfma_gemm<128, 0, 1, 0><<<dim3(MROWS / 128, VV / 128), 256, 0, stream>>>(
        hb, predT, nullptr, out_score, nullptr, MROWS, VV, HH);
    softmax_v_kernel<<<MROWS, 512, 0, stream>>>(out_score, out_prob);
}

// Round 8
// 1032.140 us; speedup vs baseline: 19.5658x; 1.0720x over previous
//
#include <hip/hip_runtime.h>
#include <math.h>

#define BB 2
#define SS 1024
#define HH 768
#define NHEAD 12
#define HDIM 64
#define NLAYER 4
#define VV 32000
#define MROWS (BB*SS)

typedef unsigned short u16;
typedef __attribute__((ext_vector_type(8))) short short8;
typedef __attribute__((ext_vector_type(4))) float f32x4;
typedef __attribute__((ext_vector_type(4))) unsigned short u16x4;

__device__ __forceinline__ u16 f2bf(float f) {
    union { float f; unsigned u; } x; x.f = f;
    unsigned r = (x.u + 0x7fff + ((x.u >> 16) & 1)) >> 16;
    return (u16)r;
}
__device__ __forceinline__ float bf2f(u16 b) {
    union { unsigned u; float f; } x; x.u = ((unsigned)b) << 16;
    return x.f;
}

__device__ __forceinline__ void gload_lds16(const u16* g, u16* l) {
    __builtin_amdgcn_global_load_lds((const __attribute__((address_space(1))) void*)g,
                                     (__attribute__((address_space(3))) void*)l, 16, 0, 0);
}

// ---------------- weight convert + transpose: W[K][N] f32 -> Wt[N][K] bf16 ----
__global__ __launch_bounds__(256) void conv_transpose(
    const float* __restrict__ W, u16* __restrict__ Wt, int K, int N) {
    int l = blockIdx.z;
    W  += (size_t)l * K * N;
    Wt += (size_t)l * K * N;
    __shared__ u16 tile[32][33];        // tile[n][k]
    int k0 = blockIdx.y * 32, n0 = blockIdx.x * 32;
    int t = threadIdx.x;                // 256
    int ky = t >> 3, nx = (t & 7) * 4;  // load: row k0+ky, cols n0+nx..+3
    float4 v = *(const float4*)(W + (size_t)(k0 + ky) * N + n0 + nx);
    tile[nx + 0][ky] = f2bf(v.x);
    tile[nx + 1][ky] = f2bf(v.y);
    tile[nx + 2][ky] = f2bf(v.z);
    tile[nx + 3][ky] = f2bf(v.w);
    __syncthreads();
    int nr = t >> 3, kc = (t & 7) * 4;  // store: row n0+nr, cols k0+kc..+3
    u16x4 o;
    o[0] = tile[nr][kc + 0]; o[1] = tile[nr][kc + 1];
    o[2] = tile[nr][kc + 2]; o[3] = tile[nr][kc + 3];
    *(u16x4*)(Wt + (size_t)(n0 + nr) * K + k0 + kc) = o;
}

// ---------------- embedding: h f32 + hb bf16 ----------------
__global__ void embed_kernel(const int* __restrict__ ids,
                             const float* __restrict__ bpe,
                             const float* __restrict__ pos,
                             float* __restrict__ h, u16* __restrict__ hb) {
    int row = blockIdx.x;
    int s = row % SS;
    int id = ids[row];
    const float4* br = (const float4*)(bpe + (size_t)id * HH);
    const float4* pr = (const float4*)(pos + (size_t)s * HH);
    float4* hr = (float4*)(h + (size_t)row * HH);
    u16x4* hbr = (u16x4*)(hb + (size_t)row * HH);
    int t = threadIdx.x;                  // 192 threads, 1 float4 each
    float4 a = br[t], c = pr[t];
    a.x += c.x; a.y += c.y; a.z += c.z; a.w += c.w;
    hr[t] = a;
    u16x4 u; u[0] = f2bf(a.x); u[1] = f2bf(a.y); u[2] = f2bf(a.z); u[3] = f2bf(a.w);
    hbr[t] = u;
}

// ---------------- MFMA GEMM: C[M][N] = A[M][K](bf16) * Wt[N][K](bf16)^T ------
// BK=64 tiles, 2-phase double-buffer, counted vmcnt (never 0 mid-loop).
// LDS rows are 128B -> T2 XOR-swizzle byte^=((row&7)<<4); global_load_lds
// writes linearly, so the SOURCE k-slot is pre-swizzled (rule #21 both-sides):
// LDS chunk (r,s) holds global slot s^(r&7); frag read applies same XOR.
template<int BM, int ACT, int WF32, int WBF>
__global__ __launch_bounds__(256) void mfma_gemm(
    const u16* __restrict__ A, const u16* __restrict__ Wt,
    const float* __restrict__ bias, float* __restrict__ C,
    u16* __restrict__ Cb, int M, int N, int K) {
    constexpr int MR = BM / 32;         // M fragments per wave
    __shared__ u16 As[2 * BM * 64];
    __shared__ u16 Bs[2 * 128 * 64];
    const int tid = threadIdx.x;
    const int lane = tid & 63;
    const int wid = tid >> 6;

    // XCD-aware bijective swizzle of flat block id
    const int nwg = gridDim.x * gridDim.y;
    int id = blockIdx.x + gridDim.x * blockIdx.y;
    int id2 = (nwg & 7) ? id : ((id & 7) * (nwg >> 3) + (id >> 3));
    const int brow = (id2 % gridDim.x) * BM;
    const int bcol = (id2 / gridDim.x) * 128;

    const int wr = (wid >> 1) * (BM / 2);
    const int wc = (wid & 1) * 64;
    f32x4 acc[MR][4] = {};

    const u16* Abase = A + (size_t)brow * K;
    const u16* Bbase = Wt + (size_t)bcol * K;
    const int lrow = lane & 15;
    const int lhi = lane >> 4;

    // stage one BK=64 tile: chunk c -> row r=c>>3, slot s=c&7; source slot s^(r&7)
    auto stage = [&](u16* Ad, u16* Bd, int kt) {
#pragma unroll
        for (int c0 = 0; c0 < BM * 8; c0 += 256) {
            int c = c0 + tid;
            int r = c >> 3, s = c & 7;
            gload_lds16(Abase + (size_t)r * K + kt + ((s ^ (r & 7)) * 8), Ad + c * 8);
        }
#pragma unroll
        for (int c0 = 0; c0 < 1024; c0 += 256) {
            int c = c0 + tid;
            int r = c >> 3, s = c & 7;
            gload_lds16(Bbase + (size_t)r * K + kt + ((s ^ (r & 7)) * 8), Bd + c * 8);
        }
    };

    const int nt = K / 64;
    stage(As, Bs, 0);
    for (int t = 0; t < nt; ++t) {
        u16* Ac = As + (t & 1) * (BM * 64);
        u16* Bc = Bs + (t & 1) * (128 * 64);
        if (t + 1 < nt) {
            stage(As + ((t + 1) & 1) * (BM * 64),
                  Bs + ((t + 1) & 1) * (128 * 64), (t + 1) * 64);
            if constexpr (BM == 128) asm volatile("s_waitcnt vmcnt(8)" ::: "memory");
            else                     asm volatile("s_waitcnt vmcnt(6)" ::: "memory");
        } else {
            asm volatile("s_waitcnt vmcnt(0)" ::: "memory");
        }
        __builtin_amdgcn_s_barrier();
        __builtin_amdgcn_sched_barrier(0);

        short8 a[MR][2], b[4][2];
#pragma unroll
        for (int m = 0; m < MR; ++m) {
            const int R = wr + m * 16 + lrow;
            char* rp = (char*)Ac + R * 128;
#pragma unroll
            for (int kk = 0; kk < 2; ++kk)
                a[m][kk] = *(const short8*)(rp + (((kk * 4 + lhi) ^ (R & 7)) * 16));
        }
#pragma unroll
        for (int n = 0; n < 4; ++n) {
            const int R = wc + n * 16 + lrow;
            char* rp = (char*)Bc + R * 128;
#pragma unroll
            for (int kk = 0; kk < 2; ++kk)
                b[n][kk] = *(const short8*)(rp + (((kk * 4 + lhi) ^ (R & 7)) * 16));
        }
        __builtin_amdgcn_s_setprio(1);
#pragma unroll
        for (int kk = 0; kk < 2; ++kk)
#pragma unroll
            for (int m = 0; m < MR; ++m)
#pragma unroll
                for (int n = 0; n < 4; ++n)
                    acc[m][n] = __builtin_amdgcn_mfma_f32_16x16x32_bf16(a[m][kk], b[n][kk], acc[m][n], 0, 0, 0);
        __builtin_amdgcn_s_setprio(0);

        __builtin_amdgcn_sched_barrier(0);
        __builtin_amdgcn_s_barrier();
    }

    const int lr4 = (lane >> 4) * 4;
#pragma unroll
    for (int n = 0; n < 4; ++n) {
        int col = bcol + wc + n * 16 + lrow;
        float bv = bias ? bias[col] : 0.f;
#pragma unroll
        for (int m = 0; m < MR; ++m) {
#pragma unroll
            for (int j = 0; j < 4; ++j) {
                int row = brow + wr + m * 16 + lr4 + j;
                float v = acc[m][n][j] + bv;
                if (ACT == 1) v = 0.5f * v * (1.f + erff(v * 0.70710678118654752f));
                if (WF32) C[(size_t)row * N + col] = v;
                if (WBF)  Cb[(size_t)row * N + col] = f2bf(v);
            }
        }
    }
}

// ---------------- MFMA flash attention (bf16 QKV input) ----------------
__global__ __launch_bounds__(256) void attn_kernel(
    const u16* __restrict__ qkvb, const float* __restrict__ seq_mask,
    u16* __restrict__ av) {
    __shared__ u16 Ks[64 * 64];
    __shared__ u16 Vt[64 * 64];
    __shared__ u16 Ps[64 * 64];
    const int qb = gridDim.x - 1 - blockIdx.x;   // heavy-first
    const int hd = blockIdx.y, b = blockIdx.z;
    const int t = threadIdx.x;
    const int lane = t & 63;
    const int w = t >> 6;
    const int lrow = lane & 15;
    const int lhi = lane >> 4;
    const int q0 = qb * 64;
    const size_t rs = 3 * HH;

    short8 aq[2];
    {
        const u16* qrow = qkvb + (size_t)(b * SS + q0 + w * 16 + lrow) * rs + hd * HDIM;
        aq[0] = *(const short8*)(qrow + lhi * 8);
        aq[1] = *(const short8*)(qrow + 32 + lhi * 8);
    }

    f32x4 o[4] = {};
    float m_[4] = {-INFINITY, -INFINITY, -INFINITY, -INFINITY};
    float l_[4] = {0.f, 0.f, 0.f, 0.f};

    const int kr = t >> 2, dc = t & 3;
    short8 kA, kB, vA, vB;
    {
        const u16* kbase = qkvb + (size_t)(b * SS + kr) * rs + HH + hd * HDIM + dc * 16;
        kA = *(const short8*)(kbase);
        kB = *(const short8*)(kbase + 8);
        vA = *(const short8*)(kbase + HH);
        vB = *(const short8*)(kbase + HH + 8);
    }

    for (int kt = 0; kt <= qb; ++kt) {
        const int k0 = kt * 64;
        __syncthreads();
        {
            char* krowp = (char*)Ks + kr * 128;
            *(short8*)(krowp + (((dc * 32 + 0)  ^ ((kr & 7) << 4)))) = kA;
            *(short8*)(krowp + (((dc * 32 + 16) ^ ((kr & 7) << 4)))) = kB;
#pragma unroll
            for (int e = 0; e < 8; ++e) {
                int d0 = dc * 16 + e;
                int d1 = dc * 16 + 8 + e;
                *(u16*)((char*)Vt + d0 * 128 + ((kr * 2) ^ ((d0 & 7) << 4))) = (u16)vA[e];
                *(u16*)((char*)Vt + d1 * 128 + ((kr * 2) ^ ((d1 & 7) << 4))) = (u16)vB[e];
            }
        }
        __syncthreads();

        if (kt < qb) {
            const u16* kbase = qkvb + (size_t)(b * SS + k0 + 64 + kr) * rs + HH + hd * HDIM + dc * 16;
            kA = *(const short8*)(kbase);
            kB = *(const short8*)(kbase + 8);
            vA = *(const short8*)(kbase + HH);
            vB = *(const short8*)(kbase + HH + 8);
        }

        f32x4 s[4] = {};
        __builtin_amdgcn_s_setprio(1);
#pragma unroll
        for (int n = 0; n < 4; ++n) {
            const int krow = n * 16 + lrow;
            char* kp = (char*)Ks + krow * 128;
#pragma unroll
            for (int c = 0; c < 2; ++c) {
                short8 bk = *(const short8*)(kp + ((c * 64 + lhi * 16) ^ ((krow & 7) << 4)));
                s[n] = __builtin_amdgcn_mfma_f32_16x16x32_bf16(aq[c], bk, s[n], 0, 0, 0);
            }
        }
        __builtin_amdgcn_s_setprio(0);

        float sm[4];
#pragma unroll
        for (int n = 0; n < 4; ++n) sm[n] = seq_mask[b * SS + k0 + n * 16 + lrow];
        const int diag = (kt == qb);
#pragma unroll
        for (int j = 0; j < 4; ++j) {
            const int qglob = q0 + w * 16 + lhi * 4 + j;
            float sv[4];
#pragma unroll
            for (int n = 0; n < 4; ++n) {
                const int kglob = k0 + n * 16 + lrow;
                float msk = (diag && kglob > qglob) ? 0.f : sm[n];
                sv[n] = s[n][j] * 0.125f + (1.f - msk) * (-1e9f);
            }
            float tm = fmaxf(fmaxf(sv[0], sv[1]), fmaxf(sv[2], sv[3]));
            tm = fmaxf(tm, __shfl_xor(tm, 1));
            tm = fmaxf(tm, __shfl_xor(tm, 2));
            tm = fmaxf(tm, __shfl_xor(tm, 4));
            tm = fmaxf(tm, __shfl_xor(tm, 8));
            float mn = fmaxf(m_[j], tm);
            float sc = __expf(m_[j] - mn);
            float ps = 0.f;
#pragma unroll
            for (int n = 0; n < 4; ++n) {
                float p = __expf(sv[n] - mn);
                s[n][j] = p;
                ps += p;
            }
            ps += __shfl_xor(ps, 1);
            ps += __shfl_xor(ps, 2);
            ps += __shfl_xor(ps, 4);
            ps += __shfl_xor(ps, 8);
            l_[j] = l_[j] * sc + ps;
            m_[j] = mn;
#pragma unroll
            for (int dn = 0; dn < 4; ++dn) o[dn][j] *= sc;
        }

#pragma unroll
        for (int j = 0; j < 4; ++j) {
            const int prow = w * 16 + lhi * 4 + j;
            char* pp = (char*)Ps + prow * 128;
#pragma unroll
            for (int n = 0; n < 4; ++n)
                *(u16*)(pp + ((n * 32 + lrow * 2) ^ ((prow & 7) << 4))) = f2bf(s[n][j]);
        }

        const int arow = w * 16 + lrow;
        char* ap_p = (char*)Ps + arow * 128;
        __builtin_amdgcn_s_setprio(1);
#pragma unroll
        for (int c = 0; c < 2; ++c) {
            short8 ap = *(const short8*)(ap_p + ((c * 64 + lhi * 16) ^ ((arow & 7) << 4)));
#pragma unroll
            for (int dn = 0; dn < 4; ++dn) {
                const int vrow = dn * 16 + lrow;
                short8 bv = *(const short8*)((char*)Vt + vrow * 128 +
                                             ((c * 64 + lhi * 16) ^ ((vrow & 7) << 4)));
                o[dn] = __builtin_amdgcn_mfma_f32_16x16x32_bf16(ap, bv, o[dn], 0, 0, 0);
            }
        }
        __builtin_amdgcn_s_setprio(0);
    }

#pragma unroll
    for (int j = 0; j < 4; ++j) {
        const int q = q0 + w * 16 + lhi * 4 + j;
        const float inv = 1.f / l_[j];
        u16* orow = av + (size_t)(b * SS + q) * HH + hd * HDIM;
#pragma unroll
        for (int dn = 0; dn < 4; ++dn)
            orow[dn * 16 + lrow] = f2bf(o[dn][j] * inv);
    }
}

// ---------------- residual add + layernorm: h f32 + hb bf16 ----------------
__global__ void add_ln_kernel(float* __restrict__ h, u16* __restrict__ hb,
                              const float* __restrict__ a,
                              const float* __restrict__ g,
                              const float* __restrict__ bta) {
    int row = blockIdx.x;
    int t = threadIdx.x;
    __shared__ float red[256];
    size_t base = (size_t)row * HH;
    float x0 = h[base + t]       + a[base + t];
    float x1 = h[base + t + 256] + a[base + t + 256];
    float x2 = h[base + t + 512] + a[base + t + 512];

    red[t] = x0 + x1 + x2;
    __syncthreads();
    for (int o = 128; o; o >>= 1) { if (t < o) red[t] += red[t + o]; __syncthreads(); }
    float mean = red[0] * (1.0f / 768.0f);
    __syncthreads();

    float d0 = x0 - mean, d1 = x1 - mean, d2 = x2 - mean;
    red[t] = d0 * d0 + d1 * d1 + d2 * d2;
    __syncthreads();
    for (int o = 128; o; o >>= 1) { if (t < o) red[t] += red[t + o]; __syncthreads(); }
    float var = red[0] * (1.0f / 768.0f);
    float inv = 1.0f / sqrtf(var + 1e-5f);

    float y0 = g[t]       * d0 * inv + bta[t];
    float y1 = g[t + 256] * d1 * inv + bta[t + 256];
    float y2 = g[t + 512] * d2 * inv + bta[t + 512];
    h[base + t] = y0;       hb[base + t] = f2bf(y0);
    h[base + t + 256] = y1; hb[base + t + 256] = f2bf(y1);
    h[base + t + 512] = y2; hb[base + t + 512] = f2bf(y2);
}

// ---------------- single-pass row softmax over V=32000 ----------------
__global__ __launch_bounds__(512) void softmax_v_kernel(
    const float* __restrict__ score, float* __restrict__ prob) {
    __shared__ u16 srow[VV];        // 64000 B
    __shared__ float red[512];
    int row = blockIdx.x;
    int t = threadIdx.x;
    const float4* sr = (const float4*)(score + (size_t)row * VV);
    float4* pr = (float4*)(prob + (size_t)row * VV);
    const int n4 = VV / 4;          // 8000

    float mx = -INFINITY;
    for (int i = t; i < n4; i += 512) {
        float4 v = sr[i];
        u16x4 u; u[0] = f2bf(v.x); u[1] = f2bf(v.y); u[2] = f2bf(v.z); u[3] = f2bf(v.w);
        *(u16x4*)(srow + i * 4) = u;
        mx = fmaxf(mx, fmaxf(fmaxf(bf2f(u[0]), bf2f(u[1])), fmaxf(bf2f(u[2]), bf2f(u[3]))));
    }
    red[t] = mx; __syncthreads();
    for (int o = 256; o; o >>= 1) { if (t < o) red[t] = fmaxf(red[t], red[t + o]); __syncthreads(); }
    mx = red[0];
    __syncthreads();

    float s = 0.f;
    for (int i = t; i < n4; i += 512) {
        u16x4 u = *(const u16x4*)(srow + i * 4);
        s += __expf(bf2f(u[0]) - mx) + __expf(bf2f(u[1]) - mx)
           + __expf(bf2f(u[2]) - mx) + __expf(bf2f(u[3]) - mx);
    }
    red[t] = s; __syncthreads();
    for (int o = 256; o; o >>= 1) { if (t < o) red[t] += red[t + o]; __syncthreads(); }
    float inv = 1.0f / red[0];

    for (int i = t; i < n4; i += 512) {
        u16x4 u = *(const u16x4*)(srow + i * 4);
        float4 o4;
        o4.x = __expf(bf2f(u[0]) - mx) * inv; o4.y = __expf(bf2f(u[1]) - mx) * inv;
        o4.z = __expf(bf2f(u[2]) - mx) * inv; o4.w = __expf(bf2f(u[3]) - mx) * inv;
        pr[i] = o4;
    }
}

extern "C" void kernel_launch(void* const* d_in, const int* in_sizes, int n_in,
                              void* d_out, int out_size, void* d_ws, size_t ws_size,
                              hipStream_t stream) {
    const int*   ids      = (const int*)d_in[0];
    const float* seq_mask = (const float*)d_in[1];
    const float* bpe      = (const float*)d_in[2];
    const float* pos      = (const float*)d_in[3];
    const float* qkv_w    = (const float*)d_in[4];
    const float* qkv_b    = (const float*)d_in[5];
    const float* res_w    = (const float*)d_in[6];
    const float* res_b    = (const float*)d_in[7];
    const float* ln1_g    = (const float*)d_in[8];
    const float* ln1_b    = (const float*)d_in[9];
    const float* ff1_w    = (const float*)d_in[10];
    const float* ff1_b    = (const float*)d_in[11];
    const float* ff2_w    = (const float*)d_in[12];
    const float* ff2_b    = (const float*)d_in[13];
    const float* ln2_g    = (const float*)d_in[14];
    const float* ln2_b    = (const float*)d_in[15];
    const float* pred_w   = (const float*)d_in[16];

    float* out_score = (float*)d_out;
    float* out_prob  = out_score + (size_t)MROWS * VV;

    // arena layout
    size_t off = 0;
    auto take = [&](size_t bytes) -> size_t {
        size_t p = off; off += (bytes + 255) & ~(size_t)255; return p;
    };
    const size_t o_qkvT = take((size_t)NLAYER * HH * 3 * HH * 2);
    const size_t o_resT = take((size_t)NLAYER * HH * HH * 2);
    const size_t o_ff1T = take((size_t)NLAYER * HH * 4 * HH * 2);
    const size_t o_ff2T = take((size_t)NLAYER * 4 * HH * HH * 2);
    const size_t o_predT = take((size_t)HH * VV * 2);
    const size_t o_h    = take((size_t)MROWS * HH * 4);
    const size_t o_a    = take((size_t)MROWS * HH * 4);
    const size_t o_qkvb = take((size_t)MROWS * 3 * HH * 2);
    const size_t o_hb   = take((size_t)MROWS * HH * 2);
    const size_t o_avb  = take((size_t)MROWS * HH * 2);
    const size_t o_midb = take((size_t)MROWS * 4 * HH * 2);
    const size_t need = off;

    char* arena = (ws_size >= need) ? (char*)d_ws : (char*)out_prob;
    u16*   qkvT = (u16*)(arena + o_qkvT);
    u16*   resT = (u16*)(arena + o_resT);
    u16*   ff1T = (u16*)(arena + o_ff1T);
    u16*   ff2T = (u16*)(arena + o_ff2T);
    u16*   predT = (u16*)(arena + o_predT);
    float* h    = (float*)(arena + o_h);
    float* a    = (float*)(arena + o_a);
    u16*   qkvb = (u16*)(arena + o_qkvb);
    u16*   hb   = (u16*)(arena + o_hb);
    u16*   avb  = (u16*)(arena + o_avb);
    u16*   midb = (u16*)(arena + o_midb);

    conv_transpose<<<dim3(3 * HH / 32, HH / 32, NLAYER), 256, 0, stream>>>(qkv_w, qkvT, HH, 3 * HH);
    conv_transpose<<<dim3(HH / 32, HH / 32, NLAYER), 256, 0, stream>>>(res_w, resT, HH, HH);
    conv_transpose<<<dim3(4 * HH / 32, HH / 32, NLAYER), 256, 0, stream>>>(ff1_w, ff1T, HH, 4 * HH);
    conv_transpose<<<dim3(HH / 32, 4 * HH / 32, NLAYER), 256, 0, stream>>>(ff2_w, ff2T, 4 * HH, HH);
    conv_transpose<<<dim3(VV / 32, HH / 32, 1), 256, 0, stream>>>(pred_w, predT, HH, VV);

    embed_kernel<<<MROWS, 192, 0, stream>>>(ids, bpe, pos, h, hb);

    for (int l = 0; l < NLAYER; ++l) {
        mfma_gemm<128, 0, 0, 1><<<dim3(MROWS / 128, 3 * HH / 128), 256, 0, stream>>>(
            hb, qkvT + (size_t)l * HH * 3 * HH, qkv_b + (size_t)l * 3 * HH,
            nullptr, qkvb, MROWS, 3 * HH, HH);
        attn_kernel<<<dim3(SS / 64, NHEAD, BB), 256, 0, stream>>>(qkvb, seq_mask, avb);
        mfma_gemm<64, 0, 1, 0><<<dim3(MROWS / 64, HH / 128), 256, 0, stream>>>(
            avb, resT + (size_t)l * HH * HH, res_b + (size_t)l * HH,
            a, nullptr, MROWS, HH, HH);
        add_ln_kernel<<<MROWS, 256, 0, stream>>>(h, hb, a,
            ln1_g + (size_t)l * HH, ln1_b + (size_t)l * HH);
        mfma_gemm<128, 1, 0, 1><<<dim3(MROWS / 128, 4 * HH / 128), 256, 0, stream>>>(
            hb, ff1T + (size_t)l * HH * 4 * HH, ff1_b + (size_t)l * 4 * HH,
            nullptr, midb, MROWS, 4 * HH, HH);
        mfma_gemm<64, 0, 1, 0><<<dim3(MROWS / 64, HH / 128), 256, 0, stream>>>(
            midb, ff2T + (size_t)l * 4 * HH * HH, ff2_b + (size_t)l * HH,
            a, nullptr, MROWS, HH, 4 * HH);
        add_ln_kernel<<<MROWS, 256, 0, stream>>>(h, hb, a,
            ln2_g + (size_t)l * HH, ln2_b + (size_t)l * HH);
    }

    mfma_gemm<128, 0, 1, 0><<<dim3(MROWS / 128, VV / 128), 256, 0, stream>>>(
        hb, predT, nullptr, out_score, nullptr, MROWS, VV, HH);
    softmax_v_kernel<<<MROWS, 512, 0, stream>>>(out_score, out_prob);
}